// Round 5
// baseline (889.888 us; speedup 1.0000x reference)
//
#include <hip/hip_runtime.h>
#include <hip/hip_bf16.h>

typedef unsigned short u16;
typedef unsigned int   u32;
typedef __attribute__((ext_vector_type(8))) short bf16x8;
typedef __attribute__((ext_vector_type(4))) float f32x4;

#define DI static __device__ __forceinline__
#define MFMA(a,b,c) __builtin_amdgcn_mfma_f32_16x16x32_bf16(a,b,c,0,0,0)

static constexpr int CB = 192;   // channels
static constexpr int NB = 4096;  // tokens
static constexpr int BB = 4;     // batch
static constexpr float SCALE = 0.07216878364870323f; // 192^-0.5

DI float b2f(u16 u){ union{u32 i; float f;} x; x.i = (u32)u << 16; return x.f; }
DI u16 f2b(float f){ union{u32 i; float f;} x; x.f = f;
  u32 r = x.i + 0x7FFFu + ((x.i >> 16) & 1u); return (u16)(r >> 16); }

// XOR swizzle for 128B-row LDS tiles (16B-granular accesses)
DI int swzb(int row, int byteInRow){ return row*128 + (byteInRow ^ ((row & 7) << 4)); }

// stage 16 bf16 elements (32 bytes) into LDS row srow at quarter q4, from fp32 or bf16 src
template<bool F32>
DI void stage16(const void* base, size_t eoff, char* dst, int srow, int q4){
  if (F32){
    const float* s = (const float*)base + eoff;
    float4 a0 = *(const float4*)(s);
    float4 a1 = *(const float4*)(s + 4);
    float4 a2 = *(const float4*)(s + 8);
    float4 a3 = *(const float4*)(s + 12);
    union { uint4 v; u16 h[8]; } r0, r1;
    r0.h[0]=f2b(a0.x); r0.h[1]=f2b(a0.y); r0.h[2]=f2b(a0.z); r0.h[3]=f2b(a0.w);
    r0.h[4]=f2b(a1.x); r0.h[5]=f2b(a1.y); r0.h[6]=f2b(a1.z); r0.h[7]=f2b(a1.w);
    r1.h[0]=f2b(a2.x); r1.h[1]=f2b(a2.y); r1.h[2]=f2b(a2.z); r1.h[3]=f2b(a2.w);
    r1.h[4]=f2b(a3.x); r1.h[5]=f2b(a3.y); r1.h[6]=f2b(a3.z); r1.h[7]=f2b(a3.w);
    *(uint4*)(dst + swzb(srow, q4*32))      = r0.v;
    *(uint4*)(dst + swzb(srow, q4*32 + 16)) = r1.v;
  } else {
    const u16* s = (const u16*)base + eoff;
    *(uint4*)(dst + swzb(srow, q4*32))      = *(const uint4*)(s);
    *(uint4*)(dst + swzb(srow, q4*32 + 16)) = *(const uint4*)(s + 8);
  }
}

// ---------------- conv weight repack: Wt[ky*K+kx][co][ci] = bf16(sr_w[co][ci][ky][kx]) -------
template<int K>
__global__ void repack_k(const float* __restrict__ w, u16* __restrict__ wt, int total){
  int i = blockIdx.x*256 + threadIdx.x;
  if (i >= total) return;
  int kk  = i / (CB*CB);
  int rem = i % (CB*CB);
  int co = rem / CB, ci = rem % CB;
  int ky = kk / K, kx = kk % K;
  wt[i] = f2b(w[((co*CB + ci)*K + ky)*K + kx]);
}

// ---------------- generic 64x64 MFMA GEMM: C = A @ W^T + bias ----------------
// CONVK: 0 = direct A rows; K>0 = implicit conv gather (sum over K*K shifts)
// EPI:   0 = bf16 out row-major [Mtot][CB]
//        1 = conv bf16 out T_pre[(b*m+pos)*CB + col]
//        2 = kv split: col<64 -> Kbuf bf16, col>=64 -> Vpre bf16
//        3 = fp32 out row-major [Mtot][CB]   (harness d_out is float32!)
struct GemmP {
  const void* A; const void* W; const float* bias;
  u16* outb; u16* outt; u16* outk; u16* outv; float* outf;
  int Mtot;    // direct: total rows
  int m;       // rows-per-batch (conv / kv split)
  int side;
  int mtiles, ntiles;
};

template<int CONVK, int EPI, bool AF32, bool WF32>
__global__ __launch_bounds__(256) void gemm_k(GemmP p){
  __shared__ uint4 ldsbuf[1024]; // 16KB
  char* ldsA = (char*)ldsbuf;
  char* ldsB = ldsA + 8192;

  const int t = threadIdx.x;
  const int w = t >> 6, l = t & 63, lr = l & 15, lg = l >> 4;

  int bid = blockIdx.x;
  int nt, mt, b = 0;
  if (CONVK > 0) { nt = bid % p.ntiles; bid /= p.ntiles; mt = bid % p.mtiles; b = bid / p.mtiles; }
  else           { nt = bid % p.ntiles; mt = bid / p.ntiles; }

  const int srow = t >> 2;          // staging row 0..63
  const int q4   = t & 3;           // quarter within 128B row

  size_t abase;   // element index of this thread's staging row (channel 0)
  if (CONVK > 0) {
    int pos = mt*64 + srow; if (pos > p.m - 1) pos = p.m - 1;
    int cy = pos / p.side, cx = pos % p.side;
    abase = (size_t)(b*NB + cy*64 + cx) * CB;
  } else {
    int row = mt*64 + srow; if (row > p.Mtot - 1) row = p.Mtot - 1;
    abase = (size_t)row * CB;
  }
  const int wrow = nt*64 + srow;

  // constant LDS read offsets
  const int aoff0 = swzb(16*w + lr, lg*16);
  const int aoff1 = swzb(16*w + lr, 64 + lg*16);
  int boff[4][2];
  #pragma unroll
  for (int f = 0; f < 4; ++f){ boff[f][0] = swzb(16*f + lr, lg*16); boff[f][1] = swzb(16*f + lr, 64 + lg*16); }

  f32x4 zero = {0.f,0.f,0.f,0.f};
  f32x4 acc[4] = {zero, zero, zero, zero};

  const int KK = (CONVK > 0) ? CONVK*CONVK : 1;
  for (int kk = 0; kk < KK; ++kk){
    size_t ashift, wbase;
    if (CONVK > 0){
      int ky = kk / CONVK, kx = kk % CONVK;
      ashift = abase + (size_t)(ky*64 + kx)*CB;
      wbase  = ((size_t)kk*CB + wrow) * CB;
    } else {
      ashift = abase;
      wbase  = (size_t)wrow * CB;
    }
    for (int c0 = 0; c0 < CB; c0 += 64){
      stage16<AF32>(p.A, ashift + c0 + q4*16, ldsA, srow, q4);
      stage16<WF32>(p.W, wbase  + c0 + q4*16, ldsB, srow, q4);
      __syncthreads();
      bf16x8 a0 = *(const bf16x8*)(ldsA + aoff0);
      bf16x8 a1 = *(const bf16x8*)(ldsA + aoff1);
      #pragma unroll
      for (int f = 0; f < 4; ++f){
        bf16x8 b0 = *(const bf16x8*)(ldsB + boff[f][0]);
        bf16x8 b1 = *(const bf16x8*)(ldsB + boff[f][1]);
        acc[f] = MFMA(a0, b0, acc[f]);
        acc[f] = MFMA(a1, b1, acc[f]);
      }
      __syncthreads();
    }
  }

  #pragma unroll
  for (int f = 0; f < 4; ++f){
    #pragma unroll
    for (int r = 0; r < 4; ++r){
      int rowt = 16*w + lg*4 + r;
      int col  = nt*64 + 16*f + lr;
      float v = acc[f][r] + p.bias[col];
      if (EPI == 0){
        int grow = mt*64 + rowt;
        if (grow < p.Mtot) p.outb[(size_t)grow*CB + col] = f2b(v);
      } else if (EPI == 1){
        int pos = mt*64 + rowt;
        if (pos < p.m) p.outt[(size_t)(b*p.m + pos)*CB + col] = f2b(v);
      } else if (EPI == 2){
        int grow = mt*64 + rowt;
        if (grow < p.Mtot){
          int bb = grow / p.m, pp = grow % p.m;
          if (col < 64) p.outk[(size_t)(bb*p.m + pp)*64 + col]        = f2b(v);
          else          p.outv[(size_t)(bb*p.m + pp)*64 + (col - 64)] = f2b(v);
        }
      } else {
        int grow = mt*64 + rowt;
        if (grow < p.Mtot) p.outf[(size_t)grow*CB + col] = v;
      }
    }
  }
}

// ---------------- LayerNorm + exact GELU, wave per position (bf16 in/out) ----------------
__global__ __launch_bounds__(256) void ln_gelu_k(const u16* __restrict__ tp,
      const float* __restrict__ g, const float* __restrict__ bt,
      u16* __restrict__ out, int rows){
  int w = threadIdx.x >> 6, l = threadIdx.x & 63;
  int p = blockIdx.x*4 + w;
  if (p >= rows) return;
  const u16* rp = tp + (size_t)p*CB;
  float x0 = b2f(rp[l]), x1 = b2f(rp[l+64]), x2 = b2f(rp[l+128]);
  float s = x0 + x1 + x2;
  #pragma unroll
  for (int d = 1; d < 64; d <<= 1) s += __shfl_xor(s, d);
  float mean = s * (1.0f/192.0f);
  float d0 = x0-mean, d1 = x1-mean, d2 = x2-mean;
  float q = d0*d0 + d1*d1 + d2*d2;
  #pragma unroll
  for (int d = 1; d < 64; d <<= 1) q += __shfl_xor(q, d);
  float rstd = rsqrtf(q * (1.0f/192.0f) + 1e-5f);
  u16* op = out + (size_t)p*CB;
  float dv[3] = {d0, d1, d2};
  #pragma unroll
  for (int i = 0; i < 3; ++i){
    int c = l + i*64;
    float xv = dv[i] * rstd * g[c] + bt[c];
    float ge = 0.5f * xv * (1.0f + erff(xv * 0.7071067811865475f));
    op[c] = f2b(ge);
  }
}

// ---------------- v' = v + depthwise3x3(v) + lc_b; write transposed [b][d][mpad] ----------------
__global__ __launch_bounds__(256) void lcconv_k(const u16* __restrict__ vpre,
      const float* __restrict__ lw, const float* __restrict__ lb,
      u16* __restrict__ vt, int m, int mpad, int side){
  int w = threadIdx.x >> 6, d = threadIdx.x & 63;
  int idx = blockIdx.x*4 + w;
  if (idx >= BB*m) return;
  int b = idx / m, p = idx % m;
  int h = p / side, x = p % side;
  float acc = b2f(vpre[(size_t)idx*64 + d]);
  float wv[9];
  #pragma unroll
  for (int j = 0; j < 9; ++j) wv[j] = lw[d*9 + j];
  #pragma unroll
  for (int dy = 0; dy < 3; ++dy){
    int hh = h + dy - 1;
    if (hh < 0 || hh >= side) continue;
    #pragma unroll
    for (int dx = 0; dx < 3; ++dx){
      int ww = x + dx - 1;
      if (ww < 0 || ww >= side) continue;
      acc += b2f(vpre[(size_t)(b*m + hh*side + ww)*64 + d]) * wv[dy*3 + dx];
    }
  }
  acc += lb[d];
  vt[(size_t)(b*64 + d)*mpad + p] = f2b(acc);
}

// ---------------- flash attention: 64 q-rows per block, 64-key chunks ----------------
__global__ __launch_bounds__(256) void attn_k(const u16* __restrict__ qall,
      const u16* __restrict__ kbuf, const u16* __restrict__ vt,
      u16* __restrict__ xh, int m, int mpad, int head){
  __shared__ uint4 lds[2048]; // 32KB: Q 8K | K 8K | V^T 8K | P 4x2K
  char* Qb = (char*)lds;
  char* Kb = Qb + 8192;
  char* Vb = Kb + 8192;
  const int t = threadIdx.x;
  const int w = t >> 6, l = t & 63, lr = l & 15, lg = l >> 4;
  char* Pb = Vb + 8192 + w*2048;
  const int b = blockIdx.x >> 6, q0 = (blockIdx.x & 63)*64;

  { // stage Q tile (rows q0..q0+63, cols head*64..+63)
    int row = t >> 2, seg = (t & 3)*32;
    const char* src = (const char*)(qall + (size_t)(b*NB + q0 + row)*CB + head*64) + seg;
    *(uint4*)(Qb + swzb(row, seg))    = *(const uint4*)src;
    *(uint4*)(Qb + swzb(row, seg+16)) = *(const uint4*)(src + 16);
  }

  const int qoff0 = swzb(16*w + lr, lg*16), qoff1 = swzb(16*w + lr, 64 + lg*16);
  int koff[4][2];
  #pragma unroll
  for (int f = 0; f < 4; ++f){ koff[f][0] = swzb(16*f + lr, lg*16); koff[f][1] = swzb(16*f + lr, 64 + lg*16); }
  const int poff0 = swzb(lr, lg*16), poff1 = swzb(lr, 64 + lg*16);

  float mrow[4] = {-1e30f,-1e30f,-1e30f,-1e30f};
  float lrow[4] = {0.f,0.f,0.f,0.f};
  f32x4 zero = {0.f,0.f,0.f,0.f};
  f32x4 oacc[4] = {zero, zero, zero, zero};

  const int nkc = (m + 63) / 64;
  for (int kc = 0; kc < nkc; ++kc){
    const int j0 = kc*64;
    __syncthreads(); // protect Kb/Vb overwrite vs prev iteration reads
    {
      int j = t >> 2, seg = (t & 3)*32;
      int jj = j0 + j; if (jj > m-1) jj = m-1;
      const char* src = (const char*)(kbuf + (size_t)(b*m + jj)*64) + seg;
      *(uint4*)(Kb + swzb(j, seg))    = *(const uint4*)src;
      *(uint4*)(Kb + swzb(j, seg+16)) = *(const uint4*)(src + 16);
      int d = j;
      const char* sv = (const char*)(vt + (size_t)(b*64 + d)*mpad + j0) + seg;
      *(uint4*)(Vb + swzb(d, seg))    = *(const uint4*)sv;
      *(uint4*)(Vb + swzb(d, seg+16)) = *(const uint4*)(sv + 16);
    }
    __syncthreads();

    // S = Q @ K^T
    f32x4 s[4] = {zero, zero, zero, zero};
    bf16x8 a0 = *(const bf16x8*)(Qb + qoff0);
    bf16x8 a1 = *(const bf16x8*)(Qb + qoff1);
    #pragma unroll
    for (int f = 0; f < 4; ++f){
      bf16x8 k0 = *(const bf16x8*)(Kb + koff[f][0]);
      bf16x8 k1 = *(const bf16x8*)(Kb + koff[f][1]);
      s[f] = MFMA(a0, k0, s[f]);
      s[f] = MFMA(a1, k1, s[f]);
    }
    // online softmax (rows lg*4+r, cols 16f+lr)
    float fac[4];
    #pragma unroll
    for (int r = 0; r < 4; ++r){
      float mx = -1e30f;
      #pragma unroll
      for (int f = 0; f < 4; ++f){
        float sv = s[f][r] * SCALE;
        int key = j0 + 16*f + lr;
        sv = (key < m) ? sv : -1e30f;
        s[f][r] = sv;
        mx = fmaxf(mx, sv);
      }
      mx = fmaxf(mx, __shfl_xor(mx, 1));
      mx = fmaxf(mx, __shfl_xor(mx, 2));
      mx = fmaxf(mx, __shfl_xor(mx, 4));
      mx = fmaxf(mx, __shfl_xor(mx, 8));
      float mold = mrow[r];
      float mnew = fmaxf(mold, mx);
      mrow[r] = mnew;
      fac[r] = __expf(mold - mnew);
      float rs = 0.f;
      #pragma unroll
      for (int f = 0; f < 4; ++f){
        float pe = __expf(s[f][r] - mnew);
        rs += pe;
        int prow = lg*4 + r, pcol = 16*f + lr;
        *(u16*)(Pb + swzb(prow, pcol*2)) = f2b(pe);
      }
      rs += __shfl_xor(rs, 1);
      rs += __shfl_xor(rs, 2);
      rs += __shfl_xor(rs, 4);
      rs += __shfl_xor(rs, 8);
      lrow[r] = lrow[r]*fac[r] + rs;
    }
    #pragma unroll
    for (int f = 0; f < 4; ++f){
      oacc[f][0] *= fac[0]; oacc[f][1] *= fac[1];
      oacc[f][2] *= fac[2]; oacc[f][3] *= fac[3];
    }
    __syncthreads(); // order Pb writes before reads (and wave join)
    // O += P @ V'
    bf16x8 p0 = *(const bf16x8*)(Pb + poff0);
    bf16x8 p1 = *(const bf16x8*)(Pb + poff1);
    #pragma unroll
    for (int f = 0; f < 4; ++f){
      bf16x8 v0 = *(const bf16x8*)(Vb + koff[f][0]);
      bf16x8 v1 = *(const bf16x8*)(Vb + koff[f][1]);
      oacc[f] = MFMA(p0, v0, oacc[f]);
      oacc[f] = MFMA(p1, v1, oacc[f]);
    }
  }

  #pragma unroll
  for (int f = 0; f < 4; ++f){
    #pragma unroll
    for (int r = 0; r < 4; ++r){
      int row = q0 + 16*w + lg*4 + r;
      int col = head*64 + 16*f + lr;
      xh[(size_t)(b*NB + row)*CB + col] = f2b(oacc[f][r] / lrow[r]);
    }
  }
}

// ---------------- host ----------------
// d_out is FLOAT32 [B*N][192] (reference output dtype). q_all (bf16, 6.29MB)
// lives in d_out's first half; dead before the final fp32 GEMM writes d_out.
// ws layout (23.2 MB, overlaid by lifetime):
//   R1 @0        (4,718,592): wt  ->  kbuf(@0, 2.03M) + vpre(@2,097,152, 2.03M)
//   R2 @4,718,592(6,096,384): tpre -> vtb
//   R3 @10,814,976(6,096,384): tbuf
//   R4 @16,911,360(6,291,456): xheads
extern "C" void kernel_launch(void* const* d_in, const int* in_sizes, int n_in,
                              void* d_out, int out_size, void* d_ws, size_t ws_size,
                              hipStream_t stream){
  const float* x     = (const float*)d_in[0];
  const float* q_w   = (const float*)d_in[1];
  const float* q_b   = (const float*)d_in[2];
  const float* kv_w  = (const float*)d_in[3];
  const float* kv_b  = (const float*)d_in[4];
  const float* sr_w[3] = {(const float*)d_in[5], (const float*)d_in[7], (const float*)d_in[9]};
  const float* sr_b[3] = {(const float*)d_in[6], (const float*)d_in[8], (const float*)d_in[10]};
  const float* ln_g[3] = {(const float*)d_in[11], (const float*)d_in[13], (const float*)d_in[15]};
  const float* ln_b[3] = {(const float*)d_in[12], (const float*)d_in[14], (const float*)d_in[16]};
  const float* lc_w[3] = {(const float*)d_in[17], (const float*)d_in[19], (const float*)d_in[21]};
  const float* lc_b[3] = {(const float*)d_in[18], (const float*)d_in[20], (const float*)d_in[22]};
  const float* nn1_w = (const float*)d_in[23];
  const float* nn1_b = (const float*)d_in[24];

  char* ws = (char*)d_ws;
  u16* q_all  = (u16*)d_out;            // bf16 scratch inside fp32 d_out
  u16* wt     = (u16*)(ws);             // R1
  u16* kbuf   = (u16*)(ws);             // R1+0 (after wt dead)
  u16* vpre   = (u16*)(ws + 2097152);   // R1+2MB
  u16* tpre   = (u16*)(ws + 4718592);   // R2
  u16* vtb    = (u16*)(ws + 4718592);   // R2 (after tpre dead)
  u16* tbuf   = (u16*)(ws + 10814976);  // R3
  u16* xheads = (u16*)(ws + 16911360);  // R4

  const int Ks[3] = {8, 4, 2}, sides[3] = {57, 61, 63};

  { // q projection: (B*N,192) = x @ q_w^T + q_b   -> q_all (bf16, in d_out)
    GemmP p{}; p.A = x; p.W = q_w; p.bias = q_b; p.outb = q_all;
    p.Mtot = BB*NB; p.m = BB*NB; p.mtiles = 256; p.ntiles = 3;
    gemm_k<0,0,true,true><<<256*3, 256, 0, stream>>>(p);
  }

  for (int i = 0; i < 3; ++i){
    const int K = Ks[i], side = sides[i], m = side*side;
    const int mpad = ((m + 64 + 7)/8)*8;
    const int tot = CB*CB*K*K;
    if (i == 0) repack_k<8><<<(tot+255)/256, 256, 0, stream>>>(sr_w[i], wt, tot);
    if (i == 1) repack_k<4><<<(tot+255)/256, 256, 0, stream>>>(sr_w[i], wt, tot);
    if (i == 2) repack_k<2><<<(tot+255)/256, 256, 0, stream>>>(sr_w[i], wt, tot);

    const int mtb = (m + 63)/64;
    GemmP pc{}; pc.A = x; pc.W = wt; pc.bias = sr_b[i]; pc.outt = tpre;
    pc.Mtot = m; pc.m = m; pc.side = side; pc.mtiles = mtb; pc.ntiles = 3;
    if (i == 0) gemm_k<8,1,true,false><<<BB*mtb*3, 256, 0, stream>>>(pc);
    if (i == 1) gemm_k<4,1,true,false><<<BB*mtb*3, 256, 0, stream>>>(pc);
    if (i == 2) gemm_k<2,1,true,false><<<BB*mtb*3, 256, 0, stream>>>(pc);

    ln_gelu_k<<<m, 256, 0, stream>>>(tpre, ln_g[i], ln_b[i], tbuf, BB*m);

    GemmP pk{}; pk.A = tbuf; pk.W = kv_w; pk.bias = kv_b; pk.outk = kbuf; pk.outv = vpre;
    pk.Mtot = BB*m; pk.m = m; pk.mtiles = (BB*m + 63)/64; pk.ntiles = 2;
    gemm_k<0,2,false,true><<<pk.mtiles*2, 256, 0, stream>>>(pk);

    lcconv_k<<<m, 256, 0, stream>>>(vpre, lc_w[i], lc_b[i], vtb, m, mpad, side);

    attn_k<<<BB*64, 256, 0, stream>>>(q_all, kbuf, vtb, xheads, m, mpad, i);
  }

  { // out = concat @ nn1_w^T + nn1_b  -> fp32 d_out (q_all dead)
    GemmP p{}; p.A = xheads; p.W = nn1_w; p.bias = nn1_b; p.outf = (float*)d_out;
    p.Mtot = BB*NB; p.m = BB*NB; p.mtiles = 256; p.ntiles = 3;
    gemm_k<0,3,false,true><<<256*3, 256, 0, stream>>>(p);
  }
}

// Round 6
// 790.636 us; speedup vs baseline: 1.1255x; 1.1255x over previous
//
#include <hip/hip_runtime.h>
#include <hip/hip_bf16.h>

typedef unsigned short u16;
typedef unsigned int   u32;
typedef __attribute__((ext_vector_type(8))) short bf16x8;
typedef __attribute__((ext_vector_type(4))) float f32x4;

#define DI static __device__ __forceinline__
#define MFMA(a,b,c) __builtin_amdgcn_mfma_f32_16x16x32_bf16(a,b,c,0,0,0)

static constexpr int CB = 192;   // channels
static constexpr int NB = 4096;  // tokens
static constexpr int BB = 4;     // batch
static constexpr float SCALE = 0.07216878364870323f; // 192^-0.5

DI float b2f(u16 u){ union{u32 i; float f;} x; x.i = (u32)u << 16; return x.f; }
DI u16 f2b(float f){ union{u32 i; float f;} x; x.f = f;
  u32 r = x.i + 0x7FFFu + ((x.i >> 16) & 1u); return (u16)(r >> 16); }

// XOR swizzle for 128B-row LDS tiles (16B-granular accesses)
DI int swzb(int row, int byteInRow){ return row*128 + (byteInRow ^ ((row & 7) << 4)); }

// stage 16 bf16 elements (32 bytes) into LDS row srow at quarter q4, from fp32 or bf16 src
template<bool F32>
DI void stage16(const void* base, size_t eoff, char* dst, int srow, int q4){
  if (F32){
    const float* s = (const float*)base + eoff;
    float4 a0 = *(const float4*)(s);
    float4 a1 = *(const float4*)(s + 4);
    float4 a2 = *(const float4*)(s + 8);
    float4 a3 = *(const float4*)(s + 12);
    union { uint4 v; u16 h[8]; } r0, r1;
    r0.h[0]=f2b(a0.x); r0.h[1]=f2b(a0.y); r0.h[2]=f2b(a0.z); r0.h[3]=f2b(a0.w);
    r0.h[4]=f2b(a1.x); r0.h[5]=f2b(a1.y); r0.h[6]=f2b(a1.z); r0.h[7]=f2b(a1.w);
    r1.h[0]=f2b(a2.x); r1.h[1]=f2b(a2.y); r1.h[2]=f2b(a2.z); r1.h[3]=f2b(a2.w);
    r1.h[4]=f2b(a3.x); r1.h[5]=f2b(a3.y); r1.h[6]=f2b(a3.z); r1.h[7]=f2b(a3.w);
    *(uint4*)(dst + swzb(srow, q4*32))      = r0.v;
    *(uint4*)(dst + swzb(srow, q4*32 + 16)) = r1.v;
  } else {
    const u16* s = (const u16*)base + eoff;
    *(uint4*)(dst + swzb(srow, q4*32))      = *(const uint4*)(s);
    *(uint4*)(dst + swzb(srow, q4*32 + 16)) = *(const uint4*)(s + 8);
  }
}

// ---------------- fp32 -> bf16 bulk convert ----------------
__global__ __launch_bounds__(256) void cvt_k(const float* __restrict__ in,
      u16* __restrict__ out, int n4){
  int i = blockIdx.x*256 + threadIdx.x;
  if (i >= n4) return;
  float4 v = ((const float4*)in)[i];
  union{ uint2 u; u16 h[4]; } r;
  r.h[0]=f2b(v.x); r.h[1]=f2b(v.y); r.h[2]=f2b(v.z); r.h[3]=f2b(v.w);
  ((uint2*)out)[i] = r.u;
}

// ---------------- conv weight repack: Wt[ky*K+kx][co][ci] = bf16(sr_w[co][ci][ky][kx]) -------
template<int K>
__global__ void repack_k(const float* __restrict__ w, u16* __restrict__ wt, int total){
  int i = blockIdx.x*256 + threadIdx.x;
  if (i >= total) return;
  int kk  = i / (CB*CB);
  int rem = i % (CB*CB);
  int co = rem / CB, ci = rem % CB;
  int ky = kk / K, kx = kk % K;
  wt[i] = f2b(w[((co*CB + ci)*K + ky)*K + kx]);
}

// ---------------- sliding-window implicit-GEMM conv ----------------
// Block = (b, oy): computes out[oy][ox 0..side)][co 0..192).
// A-window (K image rows x 64 cols x 64ch) staged ONCE per c0; W tiles
// (192co x 64ch per kk) streamed double-buffered, 1 barrier per kk.
template<int K>
__global__ __launch_bounds__(256) void conv_k(const u16* __restrict__ xb,
      const u16* __restrict__ wt, const float* __restrict__ bias,
      u16* __restrict__ out, int side, int m){
  constexpr int AR = K*64;
  __shared__ char lds[(AR + 2*192)*128];   // K8:112K  K4:80K  K2:64K
  char* Awin = lds;
  char* W0 = lds + AR*128;
  char* W1 = W0 + 192*128;

  const int t = threadIdx.x;
  const int w = t >> 6, l = t & 63, lr = l & 15, lg = l >> 4;
  const int b = blockIdx.x / side;
  const int oy = blockIdx.x % side;

  int boff[12][2];
  #pragma unroll
  for (int f = 0; f < 12; ++f){
    boff[f][0] = swzb(16*f + lr, lg*16);
    boff[f][1] = swzb(16*f + lr, 64 + lg*16);
  }

  f32x4 zero = {0.f,0.f,0.f,0.f};
  f32x4 acc[12];
  #pragma unroll
  for (int f = 0; f < 12; ++f) acc[f] = zero;

  const int rowb = 16*w + lr;       // ox (m-row) of this lane's A fragment
  const int scol = t >> 2, sq4 = t & 3;

  for (int c0 = 0; c0 < CB; c0 += 64){
    __syncthreads();   // previous c0's readers done before overwriting Awin/W0
    #pragma unroll
    for (int r = 0; r < K; ++r){
      stage16<false>(xb, ((size_t)(b*NB + (oy + r)*64 + scol))*CB + c0 + sq4*16,
                     Awin, r*64 + scol, sq4);
    }
    #pragma unroll
    for (int k = 0; k < 3; ++k){   // stage W(kk=0)
      int s = t + k*256, row = s >> 2, q4 = s & 3;
      stage16<false>(wt, ((size_t)row)*CB + c0 + q4*16, W0, row, q4);
    }
    for (int kk = 0; kk < K*K; ++kk){
      __syncthreads();             // Awin + W(kk) visible; W((kk+1)^1 buf) free
      char* Wcur = (kk & 1) ? W1 : W0;
      if (kk + 1 < K*K){
        char* Wnxt = (kk & 1) ? W0 : W1;
        #pragma unroll
        for (int k = 0; k < 3; ++k){
          int s = t + k*256, row = s >> 2, q4 = s & 3;
          stage16<false>(wt, ((size_t)(kk+1)*CB + row)*CB + c0 + q4*16, Wnxt, row, q4);
        }
      }
      int ky = kk / K, kx = kk - ky*K;
      int arow = ky*64 + rowb + kx;     // may exceed AR for masked lanes (harmless)
      int x16 = (arow & 7) << 4;
      const char* ab = Awin + arow*128;
      bf16x8 a0 = *(const bf16x8*)(ab + ((lg*16) ^ x16));
      bf16x8 a1 = *(const bf16x8*)(ab + ((64 + lg*16) ^ x16));
      #pragma unroll
      for (int f = 0; f < 12; ++f){
        bf16x8 b0v = *(const bf16x8*)(Wcur + boff[f][0]);
        bf16x8 b1v = *(const bf16x8*)(Wcur + boff[f][1]);
        acc[f] = MFMA(a0, b0v, acc[f]);
        acc[f] = MFMA(a1, b1v, acc[f]);
      }
    }
  }

  const int posb = oy*side;
  #pragma unroll
  for (int f = 0; f < 12; ++f){
    int co = 16*f + lr;
    float bv = bias[co];
    #pragma unroll
    for (int r = 0; r < 4; ++r){
      int ox = 16*w + lg*4 + r;
      if (ox < side)
        out[((size_t)(b*m + posb + ox))*CB + co] = f2b(acc[f][r] + bv);
    }
  }
}

// ---------------- generic 64x64 MFMA GEMM: C = A @ W^T + bias ----------------
// EPI: 0 = bf16 out [Mtot][CB]; 2 = kv split (k bf16 / v bf16); 3 = fp32 out [Mtot][CB]
struct GemmP {
  const void* A; const void* W; const float* bias;
  u16* outb; u16* outk; u16* outv; float* outf;
  int Mtot;
  int m;       // rows-per-batch (kv split)
  int mtiles, ntiles;
};

template<int EPI, bool AF32, bool WF32>
__global__ __launch_bounds__(256) void gemm_k(GemmP p){
  __shared__ uint4 ldsbuf[1024]; // 16KB
  char* ldsA = (char*)ldsbuf;
  char* ldsB = ldsA + 8192;

  const int t = threadIdx.x;
  const int w = t >> 6, l = t & 63, lr = l & 15, lg = l >> 4;

  int bid = blockIdx.x;
  int nt = bid % p.ntiles, mt = bid / p.ntiles;

  const int srow = t >> 2;
  const int q4   = t & 3;

  size_t abase;
  { int row = mt*64 + srow; if (row > p.Mtot - 1) row = p.Mtot - 1;
    abase = (size_t)row * CB; }
  const int wrow = nt*64 + srow;

  const int aoff0 = swzb(16*w + lr, lg*16);
  const int aoff1 = swzb(16*w + lr, 64 + lg*16);
  int boff[4][2];
  #pragma unroll
  for (int f = 0; f < 4; ++f){ boff[f][0] = swzb(16*f + lr, lg*16); boff[f][1] = swzb(16*f + lr, 64 + lg*16); }

  f32x4 zero = {0.f,0.f,0.f,0.f};
  f32x4 acc[4] = {zero, zero, zero, zero};

  size_t wbase = (size_t)wrow * CB;
  for (int c0 = 0; c0 < CB; c0 += 64){
    stage16<AF32>(p.A, abase + c0 + q4*16, ldsA, srow, q4);
    stage16<WF32>(p.W, wbase + c0 + q4*16, ldsB, srow, q4);
    __syncthreads();
    bf16x8 a0 = *(const bf16x8*)(ldsA + aoff0);
    bf16x8 a1 = *(const bf16x8*)(ldsA + aoff1);
    #pragma unroll
    for (int f = 0; f < 4; ++f){
      bf16x8 b0 = *(const bf16x8*)(ldsB + boff[f][0]);
      bf16x8 b1 = *(const bf16x8*)(ldsB + boff[f][1]);
      acc[f] = MFMA(a0, b0, acc[f]);
      acc[f] = MFMA(a1, b1, acc[f]);
    }
    __syncthreads();
  }

  #pragma unroll
  for (int f = 0; f < 4; ++f){
    #pragma unroll
    for (int r = 0; r < 4; ++r){
      int rowt = 16*w + lg*4 + r;
      int col  = nt*64 + 16*f + lr;
      float v = acc[f][r] + p.bias[col];
      int grow = mt*64 + rowt;
      if (grow >= p.Mtot) continue;
      if (EPI == 0){
        p.outb[(size_t)grow*CB + col] = f2b(v);
      } else if (EPI == 2){
        int bb = grow / p.m, pp = grow % p.m;
        if (col < 64) p.outk[(size_t)(bb*p.m + pp)*64 + col]        = f2b(v);
        else          p.outv[(size_t)(bb*p.m + pp)*64 + (col - 64)] = f2b(v);
      } else {
        p.outf[(size_t)grow*CB + col] = v;
      }
    }
  }
}

// ---------------- LayerNorm + exact GELU, wave per position (bf16 in/out) ----------------
__global__ __launch_bounds__(256) void ln_gelu_k(const u16* __restrict__ tp,
      const float* __restrict__ g, const float* __restrict__ bt,
      u16* __restrict__ out, int rows){
  int w = threadIdx.x >> 6, l = threadIdx.x & 63;
  int p = blockIdx.x*4 + w;
  if (p >= rows) return;
  const u16* rp = tp + (size_t)p*CB;
  float x0 = b2f(rp[l]), x1 = b2f(rp[l+64]), x2 = b2f(rp[l+128]);
  float s = x0 + x1 + x2;
  #pragma unroll
  for (int d = 1; d < 64; d <<= 1) s += __shfl_xor(s, d);
  float mean = s * (1.0f/192.0f);
  float d0 = x0-mean, d1 = x1-mean, d2 = x2-mean;
  float q = d0*d0 + d1*d1 + d2*d2;
  #pragma unroll
  for (int d = 1; d < 64; d <<= 1) q += __shfl_xor(q, d);
  float rstd = rsqrtf(q * (1.0f/192.0f) + 1e-5f);
  u16* op = out + (size_t)p*CB;
  float dv[3] = {d0, d1, d2};
  #pragma unroll
  for (int i = 0; i < 3; ++i){
    int c = l + i*64;
    float xv = dv[i] * rstd * g[c] + bt[c];
    float ge = 0.5f * xv * (1.0f + erff(xv * 0.7071067811865475f));
    op[c] = f2b(ge);
  }
}

// ---------------- v' = v + depthwise3x3(v) + lc_b; write transposed [b][d][mpad] ----------------
__global__ __launch_bounds__(256) void lcconv_k(const u16* __restrict__ vpre,
      const float* __restrict__ lw, const float* __restrict__ lb,
      u16* __restrict__ vt, int m, int mpad, int side){
  int w = threadIdx.x >> 6, d = threadIdx.x & 63;
  int idx = blockIdx.x*4 + w;
  if (idx >= BB*m) return;
  int b = idx / m, p = idx % m;
  int h = p / side, x = p % side;
  float acc = b2f(vpre[(size_t)idx*64 + d]);
  float wv[9];
  #pragma unroll
  for (int j = 0; j < 9; ++j) wv[j] = lw[d*9 + j];
  #pragma unroll
  for (int dy = 0; dy < 3; ++dy){
    int hh = h + dy - 1;
    if (hh < 0 || hh >= side) continue;
    #pragma unroll
    for (int dx = 0; dx < 3; ++dx){
      int ww = x + dx - 1;
      if (ww < 0 || ww >= side) continue;
      acc += b2f(vpre[(size_t)(b*m + hh*side + ww)*64 + d]) * wv[dy*3 + dx];
    }
  }
  acc += lb[d];
  vt[(size_t)(b*64 + d)*mpad + p] = f2b(acc);
}

// ---------------- flash attention: 64 q-rows per block, 64-key chunks ----------------
__global__ __launch_bounds__(256) void attn_k(const u16* __restrict__ qall,
      const u16* __restrict__ kbuf, const u16* __restrict__ vt,
      u16* __restrict__ xh, int m, int mpad, int head){
  __shared__ uint4 lds[2048]; // 32KB: Q 8K | K 8K | V^T 8K | P 4x2K
  char* Qb = (char*)lds;
  char* Kb = Qb + 8192;
  char* Vb = Kb + 8192;
  const int t = threadIdx.x;
  const int w = t >> 6, l = t & 63, lr = l & 15, lg = l >> 4;
  char* Pb = Vb + 8192 + w*2048;
  const int b = blockIdx.x >> 6, q0 = (blockIdx.x & 63)*64;

  {
    int row = t >> 2, seg = (t & 3)*32;
    const char* src = (const char*)(qall + (size_t)(b*NB + q0 + row)*CB + head*64) + seg;
    *(uint4*)(Qb + swzb(row, seg))    = *(const uint4*)src;
    *(uint4*)(Qb + swzb(row, seg+16)) = *(const uint4*)(src + 16);
  }

  const int qoff0 = swzb(16*w + lr, lg*16), qoff1 = swzb(16*w + lr, 64 + lg*16);
  int koff[4][2];
  #pragma unroll
  for (int f = 0; f < 4; ++f){ koff[f][0] = swzb(16*f + lr, lg*16); koff[f][1] = swzb(16*f + lr, 64 + lg*16); }
  const int poff0 = swzb(lr, lg*16), poff1 = swzb(lr, 64 + lg*16);

  float mrow[4] = {-1e30f,-1e30f,-1e30f,-1e30f};
  float lrow[4] = {0.f,0.f,0.f,0.f};
  f32x4 zero = {0.f,0.f,0.f,0.f};
  f32x4 oacc[4] = {zero, zero, zero, zero};

  const int nkc = (m + 63) / 64;
  for (int kc = 0; kc < nkc; ++kc){
    const int j0 = kc*64;
    __syncthreads();
    {
      int j = t >> 2, seg = (t & 3)*32;
      int jj = j0 + j; if (jj > m-1) jj = m-1;
      const char* src = (const char*)(kbuf + (size_t)(b*m + jj)*64) + seg;
      *(uint4*)(Kb + swzb(j, seg))    = *(const uint4*)src;
      *(uint4*)(Kb + swzb(j, seg+16)) = *(const uint4*)(src + 16);
      int d = j;
      const char* sv = (const char*)(vt + (size_t)(b*64 + d)*mpad + j0) + seg;
      *(uint4*)(Vb + swzb(d, seg))    = *(const uint4*)sv;
      *(uint4*)(Vb + swzb(d, seg+16)) = *(const uint4*)(sv + 16);
    }
    __syncthreads();

    f32x4 s[4] = {zero, zero, zero, zero};
    bf16x8 a0 = *(const bf16x8*)(Qb + qoff0);
    bf16x8 a1 = *(const bf16x8*)(Qb + qoff1);
    #pragma unroll
    for (int f = 0; f < 4; ++f){
      bf16x8 k0 = *(const bf16x8*)(Kb + koff[f][0]);
      bf16x8 k1 = *(const bf16x8*)(Kb + koff[f][1]);
      s[f] = MFMA(a0, k0, s[f]);
      s[f] = MFMA(a1, k1, s[f]);
    }
    float fac[4];
    #pragma unroll
    for (int r = 0; r < 4; ++r){
      float mx = -1e30f;
      #pragma unroll
      for (int f = 0; f < 4; ++f){
        float sv = s[f][r] * SCALE;
        int key = j0 + 16*f + lr;
        sv = (key < m) ? sv : -1e30f;
        s[f][r] = sv;
        mx = fmaxf(mx, sv);
      }
      mx = fmaxf(mx, __shfl_xor(mx, 1));
      mx = fmaxf(mx, __shfl_xor(mx, 2));
      mx = fmaxf(mx, __shfl_xor(mx, 4));
      mx = fmaxf(mx, __shfl_xor(mx, 8));
      float mold = mrow[r];
      float mnew = fmaxf(mold, mx);
      mrow[r] = mnew;
      fac[r] = __expf(mold - mnew);
      float rs = 0.f;
      #pragma unroll
      for (int f = 0; f < 4; ++f){
        float pe = __expf(s[f][r] - mnew);
        rs += pe;
        int prow = lg*4 + r, pcol = 16*f + lr;
        *(u16*)(Pb + swzb(prow, pcol*2)) = f2b(pe);
      }
      rs += __shfl_xor(rs, 1);
      rs += __shfl_xor(rs, 2);
      rs += __shfl_xor(rs, 4);
      rs += __shfl_xor(rs, 8);
      lrow[r] = lrow[r]*fac[r] + rs;
    }
    #pragma unroll
    for (int f = 0; f < 4; ++f){
      oacc[f][0] *= fac[0]; oacc[f][1] *= fac[1];
      oacc[f][2] *= fac[2]; oacc[f][3] *= fac[3];
    }
    __syncthreads();
    bf16x8 p0 = *(const bf16x8*)(Pb + poff0);
    bf16x8 p1 = *(const bf16x8*)(Pb + poff1);
    #pragma unroll
    for (int f = 0; f < 4; ++f){
      bf16x8 v0 = *(const bf16x8*)(Vb + koff[f][0]);
      bf16x8 v1 = *(const bf16x8*)(Vb + koff[f][1]);
      oacc[f] = MFMA(p0, v0, oacc[f]);
      oacc[f] = MFMA(p1, v1, oacc[f]);
    }
  }

  #pragma unroll
  for (int f = 0; f < 4; ++f){
    #pragma unroll
    for (int r = 0; r < 4; ++r){
      int row = q0 + 16*w + lg*4 + r;
      int col = head*64 + 16*f + lr;
      xh[(size_t)(b*NB + row)*CB + col] = f2b(oacc[f][r] / lrow[r]);
    }
  }
}

// ---------------- host ----------------
// d_out fp32 [B*N][192]. q_all (bf16 6.29MB) lives in d_out; dead before final GEMM.
// ws (29.5 MB):
//   xb     @0          (6,291,456)  bf16 x, live whole run
//   xheads @6,291,456  (6,291,456)
//   wt     @12,582,912 (4,718,592)  -> overlaid per-branch by kbuf(@+0) + vpre(@+2,032,128)
//   tpre   @17,301,504 (6,096,384)  -> overlaid by vtb after ln_gelu
//   tbuf   @23,397,888 (6,096,384)
extern "C" void kernel_launch(void* const* d_in, const int* in_sizes, int n_in,
                              void* d_out, int out_size, void* d_ws, size_t ws_size,
                              hipStream_t stream){
  const float* x     = (const float*)d_in[0];
  const float* q_w   = (const float*)d_in[1];
  const float* q_b   = (const float*)d_in[2];
  const float* kv_w  = (const float*)d_in[3];
  const float* kv_b  = (const float*)d_in[4];
  const float* sr_w[3] = {(const float*)d_in[5], (const float*)d_in[7], (const float*)d_in[9]};
  const float* sr_b[3] = {(const float*)d_in[6], (const float*)d_in[8], (const float*)d_in[10]};
  const float* ln_g[3] = {(const float*)d_in[11], (const float*)d_in[13], (const float*)d_in[15]};
  const float* ln_b[3] = {(const float*)d_in[12], (const float*)d_in[14], (const float*)d_in[16]};
  const float* lc_w[3] = {(const float*)d_in[17], (const float*)d_in[19], (const float*)d_in[21]};
  const float* lc_b[3] = {(const float*)d_in[18], (const float*)d_in[20], (const float*)d_in[22]};
  const float* nn1_w = (const float*)d_in[23];
  const float* nn1_b = (const float*)d_in[24];

  char* ws = (char*)d_ws;
  u16* q_all  = (u16*)d_out;
  u16* xb     = (u16*)(ws);
  u16* xheads = (u16*)(ws + 6291456);
  u16* wt     = (u16*)(ws + 12582912);
  u16* kbuf   = (u16*)(ws + 12582912);
  u16* vpre   = (u16*)(ws + 14615040);
  u16* tpre   = (u16*)(ws + 17301504);
  u16* vtb    = (u16*)(ws + 17301504);
  u16* tbuf   = (u16*)(ws + 23397888);

  const int Ks[3] = {8, 4, 2}, sides[3] = {57, 61, 63};

  // x -> bf16 (3,145,728 elems = 786,432 float4)
  cvt_k<<<3072, 256, 0, stream>>>(x, xb, 786432);

  { // q projection
    GemmP p{}; p.A = xb; p.W = q_w; p.bias = q_b; p.outb = q_all;
    p.Mtot = BB*NB; p.m = BB*NB; p.mtiles = 256; p.ntiles = 3;
    gemm_k<0,false,true><<<256*3, 256, 0, stream>>>(p);
  }

  for (int i = 0; i < 3; ++i){
    const int K = Ks[i], side = sides[i], m = side*side;
    const int mpad = ((m + 64 + 7)/8)*8;
    const int tot = CB*CB*K*K;
    if (i == 0) repack_k<8><<<(tot+255)/256, 256, 0, stream>>>(sr_w[i], wt, tot);
    if (i == 1) repack_k<4><<<(tot+255)/256, 256, 0, stream>>>(sr_w[i], wt, tot);
    if (i == 2) repack_k<2><<<(tot+255)/256, 256, 0, stream>>>(sr_w[i], wt, tot);

    if (i == 0) conv_k<8><<<BB*side, 256, 0, stream>>>(xb, wt, sr_b[i], tpre, side, m);
    if (i == 1) conv_k<4><<<BB*side, 256, 0, stream>>>(xb, wt, sr_b[i], tpre, side, m);
    if (i == 2) conv_k<2><<<BB*side, 256, 0, stream>>>(xb, wt, sr_b[i], tpre, side, m);

    ln_gelu_k<<<m, 256, 0, stream>>>(tpre, ln_g[i], ln_b[i], tbuf, BB*m);

    GemmP pk{}; pk.A = tbuf; pk.W = kv_w; pk.bias = kv_b; pk.outk = kbuf; pk.outv = vpre;
    pk.Mtot = BB*m; pk.m = m; pk.mtiles = (BB*m + 63)/64; pk.ntiles = 2;
    gemm_k<2,false,true><<<pk.mtiles*2, 256, 0, stream>>>(pk);

    lcconv_k<<<m, 256, 0, stream>>>(vpre, lc_w[i], lc_b[i], vtb, m, mpad, side);

    attn_k<<<BB*64, 256, 0, stream>>>(q_all, kbuf, vtb, xheads, m, mpad, i);
  }

  { // out = concat @ nn1_w^T + nn1_b -> fp32 d_out
    GemmP p{}; p.A = xheads; p.W = nn1_w; p.bias = nn1_b; p.outf = (float*)d_out;
    p.Mtot = BB*NB; p.m = BB*NB; p.mtiles = 256; p.ntiles = 3;
    gemm_k<3,false,true><<<256*3, 256, 0, stream>>>(p);
  }
}

// Round 7
// 702.306 us; speedup vs baseline: 1.2671x; 1.1258x over previous
//
#include <hip/hip_runtime.h>
#include <hip/hip_bf16.h>

typedef unsigned short u16;
typedef unsigned int   u32;
typedef __attribute__((ext_vector_type(8))) short bf16x8;
typedef __attribute__((ext_vector_type(4))) float f32x4;

#define DI static __device__ __forceinline__
#define MFMA(a,b,c) __builtin_amdgcn_mfma_f32_16x16x32_bf16(a,b,c,0,0,0)

static constexpr int CB = 192;   // channels
static constexpr int NB = 4096;  // tokens
static constexpr int BB = 4;     // batch
static constexpr float SCALE = 0.07216878364870323f; // 192^-0.5

DI float b2f(u16 u){ union{u32 i; float f;} x; x.i = (u32)u << 16; return x.f; }
DI u16 f2b(float f){ union{u32 i; float f;} x; x.f = f;
  u32 r = x.i + 0x7FFFu + ((x.i >> 16) & 1u); return (u16)(r >> 16); }

// XOR swizzle for 128B-row LDS tiles (16B-granular accesses)
DI int swzb(int row, int byteInRow){ return row*128 + (byteInRow ^ ((row & 7) << 4)); }

template<bool F32>
DI void stage16(const void* base, size_t eoff, char* dst, int srow, int q4){
  if (F32){
    const float* s = (const float*)base + eoff;
    float4 a0 = *(const float4*)(s);
    float4 a1 = *(const float4*)(s + 4);
    float4 a2 = *(const float4*)(s + 8);
    float4 a3 = *(const float4*)(s + 12);
    union { uint4 v; u16 h[8]; } r0, r1;
    r0.h[0]=f2b(a0.x); r0.h[1]=f2b(a0.y); r0.h[2]=f2b(a0.z); r0.h[3]=f2b(a0.w);
    r0.h[4]=f2b(a1.x); r0.h[5]=f2b(a1.y); r0.h[6]=f2b(a1.z); r0.h[7]=f2b(a1.w);
    r1.h[0]=f2b(a2.x); r1.h[1]=f2b(a2.y); r1.h[2]=f2b(a2.z); r1.h[3]=f2b(a2.w);
    r1.h[4]=f2b(a3.x); r1.h[5]=f2b(a3.y); r1.h[6]=f2b(a3.z); r1.h[7]=f2b(a3.w);
    *(uint4*)(dst + swzb(srow, q4*32))      = r0.v;
    *(uint4*)(dst + swzb(srow, q4*32 + 16)) = r1.v;
  } else {
    const u16* s = (const u16*)base + eoff;
    *(uint4*)(dst + swzb(srow, q4*32))      = *(const uint4*)(s);
    *(uint4*)(dst + swzb(srow, q4*32 + 16)) = *(const uint4*)(s + 8);
  }
}

// ---------------- fp32 -> bf16 bulk convert ----------------
__global__ __launch_bounds__(256) void cvt_k(const float* __restrict__ in,
      u16* __restrict__ out, int n4){
  int i = blockIdx.x*256 + threadIdx.x;
  if (i >= n4) return;
  float4 v = ((const float4*)in)[i];
  union{ uint2 u; u16 h[4]; } r;
  r.h[0]=f2b(v.x); r.h[1]=f2b(v.y); r.h[2]=f2b(v.z); r.h[3]=f2b(v.w);
  ((uint2*)out)[i] = r.u;
}

// ---------------- conv weight repack: Wt[ky*K+kx][co][ci] = bf16(sr_w[co][ci][ky][kx]) -------
template<int K>
__global__ void repack_k(const float* __restrict__ w, u16* __restrict__ wt, int total){
  int i = blockIdx.x*256 + threadIdx.x;
  if (i >= total) return;
  int kk  = i / (CB*CB);
  int rem = i % (CB*CB);
  int co = rem / CB, ci = rem % CB;
  int ky = kk / K, kx = kk % K;
  wt[i] = f2b(w[((co*CB + ci)*K + ky)*K + kx]);
}

// ---------------- sliding-window implicit-GEMM conv, 512 threads ----------------
// Block = (b, oy). 8 waves: wave-group wg = w>>2 takes co half (96 each),
// ww = w&3 takes ox quarter (16 rows). A-window staged once per c0;
// W streamed double-buffered, 1 barrier per kk.
template<int K>
__global__ __launch_bounds__(512) void conv_k(const u16* __restrict__ xb,
      const u16* __restrict__ wt, const float* __restrict__ bias,
      u16* __restrict__ out, int side, int m){
  constexpr int AR = K*64;
  __shared__ char lds[(AR + 2*192)*128];   // K8:112K  K4:80K  K2:64K
  char* Awin = lds;
  char* W0 = lds + AR*128;
  char* W1 = W0 + 192*128;

  const int t = threadIdx.x;
  const int l = t & 63, lr = l & 15, lg = l >> 4;
  const int ww = (t >> 6) & 3, wg = t >> 8;
  const int b = blockIdx.x / side;
  const int oy = blockIdx.x % side;

  int boff[6][2];
  #pragma unroll
  for (int f = 0; f < 6; ++f){
    boff[f][0] = swzb(96*wg + 16*f + lr, lg*16);
    boff[f][1] = swzb(96*wg + 16*f + lr, 64 + lg*16);
  }

  f32x4 zero = {0.f,0.f,0.f,0.f};
  f32x4 acc[6];
  #pragma unroll
  for (int f = 0; f < 6; ++f) acc[f] = zero;

  const int rowb = 16*ww + lr;       // ox of this lane's A fragment

  for (int c0 = 0; c0 < CB; c0 += 64){
    __syncthreads();   // previous c0's readers done before overwriting Awin/W0
    #pragma unroll
    for (int k = 0; k < (K*256 + 511)/512; ++k){
      int s = t + k*512;
      if (s < K*256){
        int row = s >> 2, q4 = s & 3;          // row = r*64 + scol
        int r = row >> 6, scol = row & 63;
        stage16<false>(xb, ((size_t)(b*NB + (oy + r)*64 + scol))*CB + c0 + q4*16,
                       Awin, row, q4);
      }
    }
    #pragma unroll
    for (int k = 0; k < 2; ++k){   // stage W(kk=0): 768 slots
      int s = t + k*512;
      if (s < 768){
        int row = s >> 2, q4 = s & 3;
        stage16<false>(wt, ((size_t)row)*CB + c0 + q4*16, W0, row, q4);
      }
    }
    for (int kk = 0; kk < K*K; ++kk){
      __syncthreads();             // Awin + W(kk) visible; W((kk+1)^1 buf) free
      char* Wcur = (kk & 1) ? W1 : W0;
      if (kk + 1 < K*K){
        char* Wnxt = (kk & 1) ? W0 : W1;
        #pragma unroll
        for (int k = 0; k < 2; ++k){
          int s = t + k*512;
          if (s < 768){
            int row = s >> 2, q4 = s & 3;
            stage16<false>(wt, ((size_t)(kk+1)*CB + row)*CB + c0 + q4*16, Wnxt, row, q4);
          }
        }
      }
      int ky = kk / K, kx = kk - ky*K;
      int arow = ky*64 + rowb + kx;
      int x16 = (arow & 7) << 4;
      const char* ab = Awin + arow*128;
      bf16x8 a0 = *(const bf16x8*)(ab + ((lg*16) ^ x16));
      bf16x8 a1 = *(const bf16x8*)(ab + ((64 + lg*16) ^ x16));
      #pragma unroll
      for (int f = 0; f < 6; ++f){
        bf16x8 b0v = *(const bf16x8*)(Wcur + boff[f][0]);
        bf16x8 b1v = *(const bf16x8*)(Wcur + boff[f][1]);
        acc[f] = MFMA(a0, b0v, acc[f]);
        acc[f] = MFMA(a1, b1v, acc[f]);
      }
    }
  }

  const int posb = oy*side;
  #pragma unroll
  for (int f = 0; f < 6; ++f){
    int co = 96*wg + 16*f + lr;
    float bv = bias[co];
    #pragma unroll
    for (int r = 0; r < 4; ++r){
      int ox = 16*ww + lg*4 + r;
      if (ox < side)
        out[((size_t)(b*m + posb + ox))*CB + co] = f2b(acc[f][r] + bv);
    }
  }
}

// ---------------- generic 64x64 MFMA GEMM: C = A @ W^T + bias ----------------
// EPI: 0 = bf16 out [Mtot][CB]; 2 = kv split (k bf16 / v bf16); 3 = fp32 out [Mtot][CB]
struct GemmP {
  const void* A; const void* W; const float* bias;
  u16* outb; u16* outk; u16* outv; float* outf;
  int Mtot;
  int m;       // rows-per-batch (kv split)
  int mtiles, ntiles;
};

template<int EPI, bool AF32, bool WF32>
__global__ __launch_bounds__(256) void gemm_k(GemmP p){
  __shared__ uint4 ldsbuf[1024]; // 16KB
  char* ldsA = (char*)ldsbuf;
  char* ldsB = ldsA + 8192;

  const int t = threadIdx.x;
  const int w = t >> 6, l = t & 63, lr = l & 15, lg = l >> 4;

  int bid = blockIdx.x;
  int nt = bid % p.ntiles, mt = bid / p.ntiles;

  const int srow = t >> 2;
  const int q4   = t & 3;

  size_t abase;
  { int row = mt*64 + srow; if (row > p.Mtot - 1) row = p.Mtot - 1;
    abase = (size_t)row * CB; }
  const int wrow = nt*64 + srow;

  const int aoff0 = swzb(16*w + lr, lg*16);
  const int aoff1 = swzb(16*w + lr, 64 + lg*16);
  int boff[4][2];
  #pragma unroll
  for (int f = 0; f < 4; ++f){ boff[f][0] = swzb(16*f + lr, lg*16); boff[f][1] = swzb(16*f + lr, 64 + lg*16); }

  f32x4 zero = {0.f,0.f,0.f,0.f};
  f32x4 acc[4] = {zero, zero, zero, zero};

  size_t wbase = (size_t)wrow * CB;
  for (int c0 = 0; c0 < CB; c0 += 64){
    stage16<AF32>(p.A, abase + c0 + q4*16, ldsA, srow, q4);
    stage16<WF32>(p.W, wbase + c0 + q4*16, ldsB, srow, q4);
    __syncthreads();
    bf16x8 a0 = *(const bf16x8*)(ldsA + aoff0);
    bf16x8 a1 = *(const bf16x8*)(ldsA + aoff1);
    #pragma unroll
    for (int f = 0; f < 4; ++f){
      bf16x8 b0 = *(const bf16x8*)(ldsB + boff[f][0]);
      bf16x8 b1 = *(const bf16x8*)(ldsB + boff[f][1]);
      acc[f] = MFMA(a0, b0, acc[f]);
      acc[f] = MFMA(a1, b1, acc[f]);
    }
    __syncthreads();
  }

  #pragma unroll
  for (int f = 0; f < 4; ++f){
    #pragma unroll
    for (int r = 0; r < 4; ++r){
      int rowt = 16*w + lg*4 + r;
      int col  = nt*64 + 16*f + lr;
      float v = acc[f][r] + p.bias[col];
      int grow = mt*64 + rowt;
      if (grow >= p.Mtot) continue;
      if (EPI == 0){
        p.outb[(size_t)grow*CB + col] = f2b(v);
      } else if (EPI == 2){
        int bb = grow / p.m, pp = grow % p.m;
        if (col < 64) p.outk[(size_t)(bb*p.m + pp)*64 + col]        = f2b(v);
        else          p.outv[(size_t)(bb*p.m + pp)*64 + (col - 64)] = f2b(v);
      } else {
        p.outf[(size_t)grow*CB + col] = v;
      }
    }
  }
}

// ---------------- LayerNorm + exact GELU, wave per position (bf16 in/out) ----------------
__global__ __launch_bounds__(256) void ln_gelu_k(const u16* __restrict__ tp,
      const float* __restrict__ g, const float* __restrict__ bt,
      u16* __restrict__ out, int rows){
  int w = threadIdx.x >> 6, l = threadIdx.x & 63;
  int p = blockIdx.x*4 + w;
  if (p >= rows) return;
  const u16* rp = tp + (size_t)p*CB;
  float x0 = b2f(rp[l]), x1 = b2f(rp[l+64]), x2 = b2f(rp[l+128]);
  float s = x0 + x1 + x2;
  #pragma unroll
  for (int d = 1; d < 64; d <<= 1) s += __shfl_xor(s, d);
  float mean = s * (1.0f/192.0f);
  float d0 = x0-mean, d1 = x1-mean, d2 = x2-mean;
  float q = d0*d0 + d1*d1 + d2*d2;
  #pragma unroll
  for (int d = 1; d < 64; d <<= 1) q += __shfl_xor(q, d);
  float rstd = rsqrtf(q * (1.0f/192.0f) + 1e-5f);
  u16* op = out + (size_t)p*CB;
  float dv[3] = {d0, d1, d2};
  #pragma unroll
  for (int i = 0; i < 3; ++i){
    int c = l + i*64;
    float xv = dv[i] * rstd * g[c] + bt[c];
    float ge = 0.5f * xv * (1.0f + erff(xv * 0.7071067811865475f));
    op[c] = f2b(ge);
  }
}

// ---------------- v' = v + depthwise3x3(v) + lc_b; write transposed [b][d][mpad] ----------------
__global__ __launch_bounds__(256) void lcconv_k(const u16* __restrict__ vpre,
      const float* __restrict__ lw, const float* __restrict__ lb,
      u16* __restrict__ vt, int m, int mpad, int side){
  int w = threadIdx.x >> 6, d = threadIdx.x & 63;
  int idx = blockIdx.x*4 + w;
  if (idx >= BB*m) return;
  int b = idx / m, p = idx % m;
  int h = p / side, x = p % side;
  float acc = b2f(vpre[(size_t)idx*64 + d]);
  float wv[9];
  #pragma unroll
  for (int j = 0; j < 9; ++j) wv[j] = lw[d*9 + j];
  #pragma unroll
  for (int dy = 0; dy < 3; ++dy){
    int hh = h + dy - 1;
    if (hh < 0 || hh >= side) continue;
    #pragma unroll
    for (int dx = 0; dx < 3; ++dx){
      int ww = x + dx - 1;
      if (ww < 0 || ww >= side) continue;
      acc += b2f(vpre[(size_t)(b*m + hh*side + ww)*64 + d]) * wv[dy*3 + dx];
    }
  }
  acc += lb[d];
  vt[(size_t)(b*64 + d)*mpad + p] = f2b(acc);
}

// ---------------- flash attention: 512 threads, 2 key-split wave-groups ----------------
// Wave-group g (waves 4g..4g+3) processes chunks kc ≡ g (mod 2) with its own
// K/V LDS buffers + private online-softmax state; flash merge at the end.
__global__ __launch_bounds__(512) void attn_k(const u16* __restrict__ qall,
      const u16* __restrict__ kbuf, const u16* __restrict__ vt,
      u16* __restrict__ xh, int m, int mpad, int head){
  __shared__ char lds[57344]; // Q 8K | K[2] 16K | V[2] 16K | P 8x2K
  char* Qb = lds;
  char* Kb = lds + 8192;
  char* Vb = lds + 24576;
  char* Pb = lds + 40960;
  const int t = threadIdx.x;
  const int w = t >> 6, l = t & 63, lr = l & 15, lg = l >> 4;
  const int ww = w & 3, wg = w >> 2;
  char* Kg = Kb + wg*8192;
  char* Vg = Vb + wg*8192;
  char* Pw = Pb + w*2048;
  const int b = blockIdx.x >> 6, q0 = (blockIdx.x & 63)*64;

  if (t < 256){ // stage Q tile (64 rows)
    int row = t >> 2, seg = (t & 3)*32;
    const char* src = (const char*)(qall + (size_t)(b*NB + q0 + row)*CB + head*64) + seg;
    *(uint4*)(Qb + swzb(row, seg))    = *(const uint4*)src;
    *(uint4*)(Qb + swzb(row, seg+16)) = *(const uint4*)(src + 16);
  }

  const int qoff0 = swzb(16*ww + lr, lg*16), qoff1 = swzb(16*ww + lr, 64 + lg*16);
  int koff[4][2];
  #pragma unroll
  for (int f = 0; f < 4; ++f){ koff[f][0] = swzb(16*f + lr, lg*16); koff[f][1] = swzb(16*f + lr, 64 + lg*16); }
  const int poff0 = swzb(lr, lg*16), poff1 = swzb(lr, 64 + lg*16);

  float mrow[4] = {-1e30f,-1e30f,-1e30f,-1e30f};
  float lrow[4] = {0.f,0.f,0.f,0.f};
  f32x4 zero = {0.f,0.f,0.f,0.f};
  f32x4 oacc[4] = {zero, zero, zero, zero};

  const int nkc = (m + 63) / 64;
  const int cmax = (nkc + 1) >> 1;
  const int tt = t & 255;
  for (int it = 0; it < cmax; ++it){
    const int kc = it*2 + wg;
    const bool active = kc < nkc;
    const int j0 = kc*64;
    __syncthreads(); // protect Kg/Vg overwrite vs prev iteration reads
    if (active){
      int j = tt >> 2, seg = (tt & 3)*32;
      int jj = j0 + j; if (jj > m-1) jj = m-1;
      const char* src = (const char*)(kbuf + (size_t)(b*m + jj)*64) + seg;
      *(uint4*)(Kg + swzb(j, seg))    = *(const uint4*)src;
      *(uint4*)(Kg + swzb(j, seg+16)) = *(const uint4*)(src + 16);
      int d = j;
      const char* sv = (const char*)(vt + (size_t)(b*64 + d)*mpad + j0) + seg;
      *(uint4*)(Vg + swzb(d, seg))    = *(const uint4*)sv;
      *(uint4*)(Vg + swzb(d, seg+16)) = *(const uint4*)(sv + 16);
    }
    __syncthreads();
    if (active){
      // S = Q @ K^T
      f32x4 s[4] = {zero, zero, zero, zero};
      bf16x8 a0 = *(const bf16x8*)(Qb + qoff0);
      bf16x8 a1 = *(const bf16x8*)(Qb + qoff1);
      #pragma unroll
      for (int f = 0; f < 4; ++f){
        bf16x8 k0 = *(const bf16x8*)(Kg + koff[f][0]);
        bf16x8 k1 = *(const bf16x8*)(Kg + koff[f][1]);
        s[f] = MFMA(a0, k0, s[f]);
        s[f] = MFMA(a1, k1, s[f]);
      }
      float fac[4];
      #pragma unroll
      for (int r = 0; r < 4; ++r){
        float mx = -1e30f;
        #pragma unroll
        for (int f = 0; f < 4; ++f){
          float sv = s[f][r] * SCALE;
          int key = j0 + 16*f + lr;
          sv = (key < m) ? sv : -1e30f;
          s[f][r] = sv;
          mx = fmaxf(mx, sv);
        }
        mx = fmaxf(mx, __shfl_xor(mx, 1));
        mx = fmaxf(mx, __shfl_xor(mx, 2));
        mx = fmaxf(mx, __shfl_xor(mx, 4));
        mx = fmaxf(mx, __shfl_xor(mx, 8));
        float mold = mrow[r];
        float mnew = fmaxf(mold, mx);
        mrow[r] = mnew;
        fac[r] = __expf(mold - mnew);
        float rs = 0.f;
        #pragma unroll
        for (int f = 0; f < 4; ++f){
          float pe = __expf(s[f][r] - mnew);
          rs += pe;
          int prow = lg*4 + r, pcol = 16*f + lr;
          *(u16*)(Pw + swzb(prow, pcol*2)) = f2b(pe);
        }
        rs += __shfl_xor(rs, 1);
        rs += __shfl_xor(rs, 2);
        rs += __shfl_xor(rs, 4);
        rs += __shfl_xor(rs, 8);
        lrow[r] = lrow[r]*fac[r] + rs;
      }
      #pragma unroll
      for (int f = 0; f < 4; ++f){
        oacc[f][0] *= fac[0]; oacc[f][1] *= fac[1];
        oacc[f][2] *= fac[2]; oacc[f][3] *= fac[3];
      }
    }
    __syncthreads(); // order Pw writes before reads (wave-local, but uniform)
    if (active){
      bf16x8 p0 = *(const bf16x8*)(Pw + poff0);
      bf16x8 p1 = *(const bf16x8*)(Pw + poff1);
      #pragma unroll
      for (int f = 0; f < 4; ++f){
        bf16x8 v0 = *(const bf16x8*)(Vg + koff[f][0]);
        bf16x8 v1 = *(const bf16x8*)(Vg + koff[f][1]);
        oacc[f] = MFMA(p0, v0, oacc[f]);
        oacc[f] = MFMA(p1, v1, oacc[f]);
      }
    }
  }

  // flash merge: group1 publishes state; group0 merges + writes
  __syncthreads();
  if (wg == 1){
    char* Mb = Kb + ww*6144;   // reuse K/V area (24KB for 4 waves)
    #pragma unroll
    for (int f = 0; f < 4; ++f) *(f32x4*)(Mb + l*64 + f*16) = oacc[f];
    float4 mm = {mrow[0], mrow[1], mrow[2], mrow[3]};
    *(float4*)(Mb + 4096 + l*16) = mm;
    float4 ll = {lrow[0], lrow[1], lrow[2], lrow[3]};
    *(float4*)(Mb + 5120 + l*16) = ll;
  }
  __syncthreads();
  if (wg == 0){
    char* Mb = Kb + ww*6144;
    float4 m1 = *(const float4*)(Mb + 4096 + l*16);
    float4 l1 = *(const float4*)(Mb + 5120 + l*16);
    float M1[4] = {m1.x, m1.y, m1.z, m1.w};
    float L1[4] = {l1.x, l1.y, l1.z, l1.w};
    #pragma unroll
    for (int r = 0; r < 4; ++r){
      float M = fmaxf(mrow[r], M1[r]);
      float e0 = __expf(mrow[r] - M), e1 = __expf(M1[r] - M);
      float lt = lrow[r]*e0 + L1[r]*e1;
      #pragma unroll
      for (int f = 0; f < 4; ++f){
        float o1 = ((const f32x4*)(Mb + l*64 + f*16))[0][r];
        float val = (oacc[f][r]*e0 + o1*e1) / lt;
        int row = q0 + 16*ww + lg*4 + r;
        int col = head*64 + 16*f + lr;
        xh[(size_t)(b*NB + row)*CB + col] = f2b(val);
      }
    }
  }
}

// ---------------- host ----------------
// d_out fp32 [B*N][192]. q_all (bf16 6.29MB) lives in d_out; dead before final GEMM.
// ws (29.5 MB):
//   xb     @0          (6,291,456)  bf16 x, live whole run
//   xheads @6,291,456  (6,291,456)
//   wt     @12,582,912 (4,718,592)  -> overlaid per-branch by kbuf(@+0) + vpre(@+2,032,128)
//   tpre   @17,301,504 (6,096,384)  -> overlaid by vtb after ln_gelu
//   tbuf   @23,397,888 (6,096,384)
extern "C" void kernel_launch(void* const* d_in, const int* in_sizes, int n_in,
                              void* d_out, int out_size, void* d_ws, size_t ws_size,
                              hipStream_t stream){
  const float* x     = (const float*)d_in[0];
  const float* q_w   = (const float*)d_in[1];
  const float* q_b   = (const float*)d_in[2];
  const float* kv_w  = (const float*)d_in[3];
  const float* kv_b  = (const float*)d_in[4];
  const float* sr_w[3] = {(const float*)d_in[5], (const float*)d_in[7], (const float*)d_in[9]};
  const float* sr_b[3] = {(const float*)d_in[6], (const float*)d_in[8], (const float*)d_in[10]};
  const float* ln_g[3] = {(const float*)d_in[11], (const float*)d_in[13], (const float*)d_in[15]};
  const float* ln_b[3] = {(const float*)d_in[12], (const float*)d_in[14], (const float*)d_in[16]};
  const float* lc_w[3] = {(const float*)d_in[17], (const float*)d_in[19], (const float*)d_in[21]};
  const float* lc_b[3] = {(const float*)d_in[18], (const float*)d_in[20], (const float*)d_in[22]};
  const float* nn1_w = (const float*)d_in[23];
  const float* nn1_b = (const float*)d_in[24];

  char* ws = (char*)d_ws;
  u16* q_all  = (u16*)d_out;
  u16* xb     = (u16*)(ws);
  u16* xheads = (u16*)(ws + 6291456);
  u16* wt     = (u16*)(ws + 12582912);
  u16* kbuf   = (u16*)(ws + 12582912);
  u16* vpre   = (u16*)(ws + 14615040);
  u16* tpre   = (u16*)(ws + 17301504);
  u16* vtb    = (u16*)(ws + 17301504);
  u16* tbuf   = (u16*)(ws + 23397888);

  const int Ks[3] = {8, 4, 2}, sides[3] = {57, 61, 63};

  cvt_k<<<3072, 256, 0, stream>>>(x, xb, 786432);

  { // q projection
    GemmP p{}; p.A = xb; p.W = q_w; p.bias = q_b; p.outb = q_all;
    p.Mtot = BB*NB; p.m = BB*NB; p.mtiles = 256; p.ntiles = 3;
    gemm_k<0,false,true><<<256*3, 256, 0, stream>>>(p);
  }

  for (int i = 0; i < 3; ++i){
    const int K = Ks[i], side = sides[i], m = side*side;
    const int mpad = ((m + 64 + 7)/8)*8;
    const int tot = CB*CB*K*K;
    if (i == 0) repack_k<8><<<(tot+255)/256, 256, 0, stream>>>(sr_w[i], wt, tot);
    if (i == 1) repack_k<4><<<(tot+255)/256, 256, 0, stream>>>(sr_w[i], wt, tot);
    if (i == 2) repack_k<2><<<(tot+255)/256, 256, 0, stream>>>(sr_w[i], wt, tot);

    if (i == 0) conv_k<8><<<BB*side, 512, 0, stream>>>(xb, wt, sr_b[i], tpre, side, m);
    if (i == 1) conv_k<4><<<BB*side, 512, 0, stream>>>(xb, wt, sr_b[i], tpre, side, m);
    if (i == 2) conv_k<2><<<BB*side, 512, 0, stream>>>(xb, wt, sr_b[i], tpre, side, m);

    ln_gelu_k<<<m, 256, 0, stream>>>(tpre, ln_g[i], ln_b[i], tbuf, BB*m);

    GemmP pk{}; pk.A = tbuf; pk.W = kv_w; pk.bias = kv_b; pk.outk = kbuf; pk.outv = vpre;
    pk.Mtot = BB*m; pk.m = m; pk.mtiles = (BB*m + 63)/64; pk.ntiles = 2;
    gemm_k<2,false,true><<<pk.mtiles*2, 256, 0, stream>>>(pk);

    lcconv_k<<<m, 256, 0, stream>>>(vpre, lc_w[i], lc_b[i], vtb, m, mpad, side);

    attn_k<<<BB*64, 512, 0, stream>>>(q_all, kbuf, vtb, xheads, m, mpad, i);
  }

  { // out = concat @ nn1_w^T + nn1_b -> fp32 d_out
    GemmP p{}; p.A = xheads; p.W = nn1_w; p.bias = nn1_b; p.outf = (float*)d_out;
    p.Mtot = BB*NB; p.m = BB*NB; p.mtiles = 256; p.ntiles = 3;
    gemm_k<3,false,true><<<256*3, 256, 0, stream>>>(p);
  }
}

// Round 9
// 682.514 us; speedup vs baseline: 1.3038x; 1.0290x over previous
//
#include <hip/hip_runtime.h>
#include <hip/hip_bf16.h>

typedef unsigned short u16;
typedef unsigned int   u32;
typedef __attribute__((ext_vector_type(8))) short bf16x8;
typedef __attribute__((ext_vector_type(4))) float f32x4;

#define DI static __device__ __forceinline__
#define MFMA(a,b,c) __builtin_amdgcn_mfma_f32_16x16x32_bf16(a,b,c,0,0,0)

static constexpr int CB = 192;   // channels
static constexpr int NB = 4096;  // tokens
static constexpr int BB = 4;     // batch
static constexpr float SCALE = 0.07216878364870323f; // 192^-0.5

DI float b2f(u16 u){ union{u32 i; float f;} x; x.i = (u32)u << 16; return x.f; }
DI u16 f2b(float f){ union{u32 i; float f;} x; x.f = f;
  u32 r = x.i + 0x7FFFu + ((x.i >> 16) & 1u); return (u16)(r >> 16); }

// XOR swizzle for 128B-row LDS tiles (16B-granular accesses)
DI int swzb(int row, int byteInRow){ return row*128 + (byteInRow ^ ((row & 7) << 4)); }

template<bool F32>
DI void stage16(const void* base, size_t eoff, char* dst, int srow, int q4){
  if (F32){
    const float* s = (const float*)base + eoff;
    float4 a0 = *(const float4*)(s);
    float4 a1 = *(const float4*)(s + 4);
    float4 a2 = *(const float4*)(s + 8);
    float4 a3 = *(const float4*)(s + 12);
    union { uint4 v; u16 h[8]; } r0, r1;
    r0.h[0]=f2b(a0.x); r0.h[1]=f2b(a0.y); r0.h[2]=f2b(a0.z); r0.h[3]=f2b(a0.w);
    r0.h[4]=f2b(a1.x); r0.h[5]=f2b(a1.y); r0.h[6]=f2b(a1.z); r0.h[7]=f2b(a1.w);
    r1.h[0]=f2b(a2.x); r1.h[1]=f2b(a2.y); r1.h[2]=f2b(a2.z); r1.h[3]=f2b(a2.w);
    r1.h[4]=f2b(a3.x); r1.h[5]=f2b(a3.y); r1.h[6]=f2b(a3.z); r1.h[7]=f2b(a3.w);
    *(uint4*)(dst + swzb(srow, q4*32))      = r0.v;
    *(uint4*)(dst + swzb(srow, q4*32 + 16)) = r1.v;
  } else {
    const u16* s = (const u16*)base + eoff;
    *(uint4*)(dst + swzb(srow, q4*32))      = *(const uint4*)(s);
    *(uint4*)(dst + swzb(srow, q4*32 + 16)) = *(const uint4*)(s + 8);
  }
}

// ---------------- fp32 -> bf16 bulk convert ----------------
__global__ __launch_bounds__(256) void cvt_k(const float* __restrict__ in,
      u16* __restrict__ out, int n4){
  int i = blockIdx.x*256 + threadIdx.x;
  if (i >= n4) return;
  float4 v = ((const float4*)in)[i];
  union{ uint2 u; u16 h[4]; } r;
  r.h[0]=f2b(v.x); r.h[1]=f2b(v.y); r.h[2]=f2b(v.z); r.h[3]=f2b(v.w);
  ((uint2*)out)[i] = r.u;
}

// ---------------- conv weight repack: Wt[kk][co][ci] = bf16(sr_w[co][ci][kk]) ----------------
// thread = rem (co*CB+ci): per-thread contiguous reads (L1-resident), coalesced writes.
template<int K>
__global__ __launch_bounds__(256) void repack_k(const float* __restrict__ w,
      u16* __restrict__ wt){
  int rem = blockIdx.x*256 + threadIdx.x;
  if (rem >= CB*CB) return;
  const float* src = w + (size_t)rem*K*K;
  #pragma unroll
  for (int kk = 0; kk < K*K; ++kk)
    wt[(size_t)kk*CB*CB + rem] = f2b(src[kk]);
}

// ---------------- conv: ky-sliced sliding window, N-split 96-co halves ----------------
// Block = (b, oy, nh). 4 waves: wa = ox half (32), wbh = co half-of-96 (48).
// A: one image-row slice (72 cols x 64ch, padded), double-buffered, staged per ky.
// W: 96co x 64ch tile double-buffered, staged per phase. 1 barrier/phase.
template<int K>
__global__ __launch_bounds__(256) void conv_k(const u16* __restrict__ xb,
      const u16* __restrict__ wt, const float* __restrict__ bias,
      u16* __restrict__ out, int side, int m){
  __shared__ char lds[43008]; // A 2x9216 | W 2x12288
  char* Ab0 = lds;
  char* Ab1 = lds + 9216;
  char* Wb0 = lds + 18432;
  char* Wb1 = lds + 30720;

  const int t = threadIdx.x;
  const int l = t & 63, lr = l & 15, lg = l >> 4;
  const int w = t >> 6;
  const int wa = w & 1, wbh = w >> 1;

  int bid = blockIdx.x;
  const int nh = bid & 1; bid >>= 1;
  const int b = bid / side;
  const int oy = bid % side;

  int boff[3][2];
  #pragma unroll
  for (int f = 0; f < 3; ++f){
    int row = wbh*48 + f*16 + lr;
    boff[f][0] = swzb(row, lg*16);
    boff[f][1] = swzb(row, 64 + lg*16);
  }

  f32x4 zero = {0.f,0.f,0.f,0.f};
  f32x4 acc[2][3];
  #pragma unroll
  for (int fa = 0; fa < 2; ++fa)
    #pragma unroll
    for (int fb = 0; fb < 3; ++fb) acc[fa][fb] = zero;

  const int sr = t >> 2, sq = t & 3;

  auto STAGEW = [&](int kkg, int c0, char* dst){
    stage16<false>(wt, ((size_t)kkg*CB + nh*96 + sr)*CB + c0 + sq*16, dst, sr, sq);
    if (t < 128){
      int r2 = sr + 64;
      stage16<false>(wt, ((size_t)kkg*CB + nh*96 + r2)*CB + c0 + sq*16, dst, r2, sq);
    }
  };
  auto STAGEA = [&](int ky, int c0, char* dst){
    int cc = sr > 63 ? 63 : sr;
    stage16<false>(xb, ((size_t)(b*NB + (oy+ky)*64 + cc))*CB + c0 + sq*16, dst, sr, sq);
    if (t < 32){
      int r2 = sr + 64;  // rows 64..71 (pad; only feeds discarded ox)
      stage16<false>(xb, ((size_t)(b*NB + (oy+ky)*64 + 63))*CB + c0 + sq*16, dst, r2, sq);
    }
  };

  STAGEA(0, 0, Ab0);
  STAGEW(0, 0, Wb0);
  const int NPH = 3*K*K;
  for (int g = 0; g < NPH; ++g){
    __syncthreads();
    int c0i = g/(K*K); int rem = g - c0i*K*K; int kx = rem % K;
    int gn = g + 1;
    if (gn < NPH){
      int c0n = gn/(K*K); int remn = gn - c0n*K*K;
      STAGEW(remn, c0n*64, (gn & 1) ? Wb1 : Wb0);
      if ((remn % K) == 0)
        STAGEA(remn / K, c0n*64, ((gn/K) & 1) ? Ab1 : Ab0);
    }
    char* Wc = (g & 1) ? Wb1 : Wb0;
    bf16x8 wf[3][2];
    #pragma unroll
    for (int f = 0; f < 3; ++f){
      wf[f][0] = *(const bf16x8*)(Wc + boff[f][0]);
      wf[f][1] = *(const bf16x8*)(Wc + boff[f][1]);
    }
    char* Ac = ((g/K) & 1) ? Ab1 : Ab0;
    #pragma unroll
    for (int fa = 0; fa < 2; ++fa){
      int c = wa*32 + fa*16 + lr + kx;
      int x16 = (c & 7) << 4;
      const char* ab = Ac + c*128;
      bf16x8 a0 = *(const bf16x8*)(ab + ((lg*16) ^ x16));
      bf16x8 a1 = *(const bf16x8*)(ab + ((64 + lg*16) ^ x16));
      #pragma unroll
      for (int fb = 0; fb < 3; ++fb){
        acc[fa][fb] = MFMA(a0, wf[fb][0], acc[fa][fb]);
        acc[fa][fb] = MFMA(a1, wf[fb][1], acc[fa][fb]);
      }
    }
  }

  const int posb = oy*side;
  #pragma unroll
  for (int fb = 0; fb < 3; ++fb){
    int co = nh*96 + wbh*48 + fb*16 + lr;
    float bv = bias[co];
    #pragma unroll
    for (int fa = 0; fa < 2; ++fa){
      #pragma unroll
      for (int r = 0; r < 4; ++r){
        int ox = wa*32 + fa*16 + lg*4 + r;
        if (ox < side)
          out[((size_t)(b*m + posb + ox))*CB + co] = f2b(acc[fa][fb][r] + bv);
      }
    }
  }
}

// ---------------- generic 64x64 MFMA GEMM: C = A @ W^T + bias ----------------
// EPI: 0 = bf16 out [Mtot][CB]; 2 = kv split (k bf16 / v bf16); 3 = fp32 out [Mtot][CB]
struct GemmP {
  const void* A; const void* W; const float* bias;
  u16* outb; u16* outk; u16* outv; float* outf;
  int Mtot;
  int m;       // rows-per-batch (kv split)
  int mtiles, ntiles;
};

template<int EPI, bool AF32, bool WF32>
__global__ __launch_bounds__(256) void gemm_k(GemmP p){
  __shared__ uint4 ldsbuf[1024]; // 16KB
  char* ldsA = (char*)ldsbuf;
  char* ldsB = ldsA + 8192;

  const int t = threadIdx.x;
  const int w = t >> 6, l = t & 63, lr = l & 15, lg = l >> 4;

  int bid = blockIdx.x;
  int nt = bid % p.ntiles, mt = bid / p.ntiles;

  const int srow = t >> 2;
  const int q4   = t & 3;

  size_t abase;
  { int row = mt*64 + srow; if (row > p.Mtot - 1) row = p.Mtot - 1;
    abase = (size_t)row * CB; }
  const int wrow = nt*64 + srow;

  const int aoff0 = swzb(16*w + lr, lg*16);
  const int aoff1 = swzb(16*w + lr, 64 + lg*16);
  int boff[4][2];
  #pragma unroll
  for (int f = 0; f < 4; ++f){ boff[f][0] = swzb(16*f + lr, lg*16); boff[f][1] = swzb(16*f + lr, 64 + lg*16); }

  f32x4 zero = {0.f,0.f,0.f,0.f};
  f32x4 acc[4] = {zero, zero, zero, zero};

  size_t wbase = (size_t)wrow * CB;
  for (int c0 = 0; c0 < CB; c0 += 64){
    stage16<AF32>(p.A, abase + c0 + q4*16, ldsA, srow, q4);
    stage16<WF32>(p.W, wbase + c0 + q4*16, ldsB, srow, q4);
    __syncthreads();
    bf16x8 a0 = *(const bf16x8*)(ldsA + aoff0);
    bf16x8 a1 = *(const bf16x8*)(ldsA + aoff1);
    #pragma unroll
    for (int f = 0; f < 4; ++f){
      bf16x8 b0 = *(const bf16x8*)(ldsB + boff[f][0]);
      bf16x8 b1 = *(const bf16x8*)(ldsB + boff[f][1]);
      acc[f] = MFMA(a0, b0, acc[f]);
      acc[f] = MFMA(a1, b1, acc[f]);
    }
    __syncthreads();
  }

  #pragma unroll
  for (int f = 0; f < 4; ++f){
    #pragma unroll
    for (int r = 0; r < 4; ++r){
      int rowt = 16*w + lg*4 + r;
      int col  = nt*64 + 16*f + lr;
      float v = acc[f][r] + p.bias[col];
      int grow = mt*64 + rowt;
      if (grow >= p.Mtot) continue;
      if (EPI == 0){
        p.outb[(size_t)grow*CB + col] = f2b(v);
      } else if (EPI == 2){
        int bb = grow / p.m, pp = grow % p.m;
        if (col < 64) p.outk[(size_t)(bb*p.m + pp)*64 + col]        = f2b(v);
        else          p.outv[(size_t)(bb*p.m + pp)*64 + (col - 64)] = f2b(v);
      } else {
        p.outf[(size_t)grow*CB + col] = v;
      }
    }
  }
}

// ---------------- LayerNorm + exact GELU, wave per position (bf16 in/out) ----------------
__global__ __launch_bounds__(256) void ln_gelu_k(const u16* __restrict__ tp,
      const float* __restrict__ g, const float* __restrict__ bt,
      u16* __restrict__ out, int rows){
  int w = threadIdx.x >> 6, l = threadIdx.x & 63;
  int p = blockIdx.x*4 + w;
  if (p >= rows) return;
  const u16* rp = tp + (size_t)p*CB;
  float x0 = b2f(rp[l]), x1 = b2f(rp[l+64]), x2 = b2f(rp[l+128]);
  float s = x0 + x1 + x2;
  #pragma unroll
  for (int d = 1; d < 64; d <<= 1) s += __shfl_xor(s, d);
  float mean = s * (1.0f/192.0f);
  float d0 = x0-mean, d1 = x1-mean, d2 = x2-mean;
  float q = d0*d0 + d1*d1 + d2*d2;
  #pragma unroll
  for (int d = 1; d < 64; d <<= 1) q += __shfl_xor(q, d);
  float rstd = rsqrtf(q * (1.0f/192.0f) + 1e-5f);
  u16* op = out + (size_t)p*CB;
  float dv[3] = {d0, d1, d2};
  #pragma unroll
  for (int i = 0; i < 3; ++i){
    int c = l + i*64;
    float xv = dv[i] * rstd * g[c] + bt[c];
    float ge = 0.5f * xv * (1.0f + erff(xv * 0.7071067811865475f));
    op[c] = f2b(ge);
  }
}

// ---------------- v' = v + depthwise3x3(v) + lc_b; write transposed [b][d][mpad] ----------------
__global__ __launch_bounds__(256) void lcconv_k(const u16* __restrict__ vpre,
      const float* __restrict__ lw, const float* __restrict__ lb,
      u16* __restrict__ vt, int m, int mpad, int side){
  int w = threadIdx.x >> 6, d = threadIdx.x & 63;
  int idx = blockIdx.x*4 + w;
  if (idx >= BB*m) return;
  int b = idx / m, p = idx % m;
  int h = p / side, x = p % side;
  float acc = b2f(vpre[(size_t)idx*64 + d]);
  float wv[9];
  #pragma unroll
  for (int j = 0; j < 9; ++j) wv[j] = lw[d*9 + j];
  #pragma unroll
  for (int dy = 0; dy < 3; ++dy){
    int hh = h + dy - 1;
    if (hh < 0 || hh >= side) continue;
    #pragma unroll
    for (int dx = 0; dx < 3; ++dx){
      int ww = x + dx - 1;
      if (ww < 0 || ww >= side) continue;
      acc += b2f(vpre[(size_t)(b*m + hh*side + ww)*64 + d]) * wv[dy*3 + dx];
    }
  }
  acc += lb[d];
  vt[(size_t)(b*64 + d)*mpad + p] = f2b(acc);
}

// ---------------- flash attention: 512 threads, 2 key-split wave-groups ----------------
__global__ __launch_bounds__(512) void attn_k(const u16* __restrict__ qall,
      const u16* __restrict__ kbuf, const u16* __restrict__ vt,
      u16* __restrict__ xh, int m, int mpad, int head){
  __shared__ char lds[57344]; // Q 8K | K[2] 16K | V[2] 16K | P 8x2K
  char* Qb = lds;
  char* Kb = lds + 8192;
  char* Vb = lds + 24576;
  char* Pb = lds + 40960;
  const int t = threadIdx.x;
  const int w = t >> 6, l = t & 63, lr = l & 15, lg = l >> 4;
  const int ww = w & 3, wg = w >> 2;
  char* Kg = Kb + wg*8192;
  char* Vg = Vb + wg*8192;
  char* Pw = Pb + w*2048;
  const int b = blockIdx.x >> 6, q0 = (blockIdx.x & 63)*64;

  if (t < 256){
    int row = t >> 2, seg = (t & 3)*32;
    const char* src = (const char*)(qall + (size_t)(b*NB + q0 + row)*CB + head*64) + seg;
    *(uint4*)(Qb + swzb(row, seg))    = *(const uint4*)src;
    *(uint4*)(Qb + swzb(row, seg+16)) = *(const uint4*)(src + 16);
  }

  const int qoff0 = swzb(16*ww + lr, lg*16), qoff1 = swzb(16*ww + lr, 64 + lg*16);
  int koff[4][2];
  #pragma unroll
  for (int f = 0; f < 4; ++f){ koff[f][0] = swzb(16*f + lr, lg*16); koff[f][1] = swzb(16*f + lr, 64 + lg*16); }
  const int poff0 = swzb(lr, lg*16), poff1 = swzb(lr, 64 + lg*16);

  float mrow[4] = {-1e30f,-1e30f,-1e30f,-1e30f};
  float lrow[4] = {0.f,0.f,0.f,0.f};
  f32x4 zero = {0.f,0.f,0.f,0.f};
  f32x4 oacc[4] = {zero, zero, zero, zero};

  const int nkc = (m + 63) / 64;
  const int cmax = (nkc + 1) >> 1;
  const int tt = t & 255;
  for (int it = 0; it < cmax; ++it){
    const int kc = it*2 + wg;
    const bool active = kc < nkc;
    const int j0 = kc*64;
    __syncthreads();
    if (active){
      int j = tt >> 2, seg = (tt & 3)*32;
      int jj = j0 + j; if (jj > m-1) jj = m-1;
      const char* src = (const char*)(kbuf + (size_t)(b*m + jj)*64) + seg;
      *(uint4*)(Kg + swzb(j, seg))    = *(const uint4*)src;
      *(uint4*)(Kg + swzb(j, seg+16)) = *(const uint4*)(src + 16);
      int d = j;
      const char* sv = (const char*)(vt + (size_t)(b*64 + d)*mpad + j0) + seg;
      *(uint4*)(Vg + swzb(d, seg))    = *(const uint4*)sv;
      *(uint4*)(Vg + swzb(d, seg+16)) = *(const uint4*)(sv + 16);
    }
    __syncthreads();
    if (active){
      f32x4 s[4] = {zero, zero, zero, zero};
      bf16x8 a0 = *(const bf16x8*)(Qb + qoff0);
      bf16x8 a1 = *(const bf16x8*)(Qb + qoff1);
      #pragma unroll
      for (int f = 0; f < 4; ++f){
        bf16x8 k0 = *(const bf16x8*)(Kg + koff[f][0]);
        bf16x8 k1 = *(const bf16x8*)(Kg + koff[f][1]);
        s[f] = MFMA(a0, k0, s[f]);
        s[f] = MFMA(a1, k1, s[f]);
      }
      float fac[4];
      #pragma unroll
      for (int r = 0; r < 4; ++r){
        float mx = -1e30f;
        #pragma unroll
        for (int f = 0; f < 4; ++f){
          float sv = s[f][r] * SCALE;
          int key = j0 + 16*f + lr;
          sv = (key < m) ? sv : -1e30f;
          s[f][r] = sv;
          mx = fmaxf(mx, sv);
        }
        mx = fmaxf(mx, __shfl_xor(mx, 1));
        mx = fmaxf(mx, __shfl_xor(mx, 2));
        mx = fmaxf(mx, __shfl_xor(mx, 4));
        mx = fmaxf(mx, __shfl_xor(mx, 8));
        float mold = mrow[r];
        float mnew = fmaxf(mold, mx);
        mrow[r] = mnew;
        fac[r] = __expf(mold - mnew);
        float rs = 0.f;
        #pragma unroll
        for (int f = 0; f < 4; ++f){
          float pe = __expf(s[f][r] - mnew);
          rs += pe;
          int prow = lg*4 + r, pcol = 16*f + lr;
          *(u16*)(Pw + swzb(prow, pcol*2)) = f2b(pe);
        }
        rs += __shfl_xor(rs, 1);
        rs += __shfl_xor(rs, 2);
        rs += __shfl_xor(rs, 4);
        rs += __shfl_xor(rs, 8);
        lrow[r] = lrow[r]*fac[r] + rs;
      }
      #pragma unroll
      for (int f = 0; f < 4; ++f){
        oacc[f][0] *= fac[0]; oacc[f][1] *= fac[1];
        oacc[f][2] *= fac[2]; oacc[f][3] *= fac[3];
      }
    }
    __syncthreads();
    if (active){
      bf16x8 p0 = *(const bf16x8*)(Pw + poff0);
      bf16x8 p1 = *(const bf16x8*)(Pw + poff1);
      #pragma unroll
      for (int f = 0; f < 4; ++f){
        bf16x8 v0 = *(const bf16x8*)(Vg + koff[f][0]);
        bf16x8 v1 = *(const bf16x8*)(Vg + koff[f][1]);
        oacc[f] = MFMA(p0, v0, oacc[f]);
        oacc[f] = MFMA(p1, v1, oacc[f]);
      }
    }
  }

  __syncthreads();
  if (wg == 1){
    char* Mb = Kb + ww*6144;
    #pragma unroll
    for (int f = 0; f < 4; ++f) *(f32x4*)(Mb + l*64 + f*16) = oacc[f];
    float4 mm = {mrow[0], mrow[1], mrow[2], mrow[3]};
    *(float4*)(Mb + 4096 + l*16) = mm;
    float4 ll = {lrow[0], lrow[1], lrow[2], lrow[3]};
    *(float4*)(Mb + 5120 + l*16) = ll;
  }
  __syncthreads();
  if (wg == 0){
    char* Mb = Kb + ww*6144;
    float4 m1 = *(const float4*)(Mb + 4096 + l*16);
    float4 l1 = *(const float4*)(Mb + 5120 + l*16);
    float M1[4] = {m1.x, m1.y, m1.z, m1.w};
    float L1[4] = {l1.x, l1.y, l1.z, l1.w};
    #pragma unroll
    for (int r = 0; r < 4; ++r){
      float M = fmaxf(mrow[r], M1[r]);
      float e0 = __expf(mrow[r] - M), e1 = __expf(M1[r] - M);
      float lt = lrow[r]*e0 + L1[r]*e1;
      #pragma unroll
      for (int f = 0; f < 4; ++f){
        float o1 = ((const f32x4*)(Mb + l*64 + f*16))[0][r];
        float val = (oacc[f][r]*e0 + o1*e1) / lt;
        int row = q0 + 16*ww + lg*4 + r;
        int col = head*64 + 16*f + lr;
        xh[(size_t)(b*NB + row)*CB + col] = f2b(val);
      }
    }
  }
}

// ---------------- host ----------------
// d_out fp32 [B*N][192]. q_all (bf16 6.29MB) lives in d_out; dead before final GEMM.
// ws (29.5 MB): xb 6.29 | xheads 6.29 | wt 4.72 (kbuf+vpre overlay after conv) |
//               tpre 6.10 (vtb overlay after ln) | tbuf 6.10
extern "C" void kernel_launch(void* const* d_in, const int* in_sizes, int n_in,
                              void* d_out, int out_size, void* d_ws, size_t ws_size,
                              hipStream_t stream){
  const float* x     = (const float*)d_in[0];
  const float* q_w   = (const float*)d_in[1];
  const float* q_b   = (const float*)d_in[2];
  const float* kv_w  = (const float*)d_in[3];
  const float* kv_b  = (const float*)d_in[4];
  const float* sr_w[3] = {(const float*)d_in[5], (const float*)d_in[7], (const float*)d_in[9]};
  const float* sr_b[3] = {(const float*)d_in[6], (const float*)d_in[8], (const float*)d_in[10]};
  const float* ln_g[3] = {(const float*)d_in[11], (const float*)d_in[13], (const float*)d_in[15]};
  const float* ln_b[3] = {(const float*)d_in[12], (const float*)d_in[14], (const float*)d_in[16]};
  const float* lc_w[3] = {(const float*)d_in[17], (const float*)d_in[19], (const float*)d_in[21]};
  const float* lc_b[3] = {(const float*)d_in[18], (const float*)d_in[20], (const float*)d_in[22]};
  const float* nn1_w = (const float*)d_in[23];
  const float* nn1_b = (const float*)d_in[24];

  char* ws = (char*)d_ws;
  u16* q_all  = (u16*)d_out;
  u16* xb     = (u16*)(ws);
  u16* xheads = (u16*)(ws + 6291456);
  u16* wt     = (u16*)(ws + 12582912);
  u16* kbuf   = (u16*)(ws + 12582912);
  u16* vpre   = (u16*)(ws + 14615040);
  u16* tpre   = (u16*)(ws + 17301504);
  u16* vtb    = (u16*)(ws + 17301504);
  u16* tbuf   = (u16*)(ws + 23397888);

  const int Ks[3] = {8, 4, 2}, sides[3] = {57, 61, 63};

  cvt_k<<<3072, 256, 0, stream>>>(x, xb, 786432);

  { // q projection
    GemmP p{}; p.A = xb; p.W = q_w; p.bias = q_b; p.outb = q_all;
    p.Mtot = BB*NB; p.m = BB*NB; p.mtiles = 256; p.ntiles = 3;
    gemm_k<0,false,true><<<256*3, 256, 0, stream>>>(p);
  }

  for (int i = 0; i < 3; ++i){
    const int K = Ks[i], side = sides[i], m = side*side;
    const int mpad = ((m + 64 + 7)/8)*8;
    if (i == 0) repack_k<8><<<144, 256, 0, stream>>>(sr_w[i], wt);
    if (i == 1) repack_k<4><<<144, 256, 0, stream>>>(sr_w[i], wt);
    if (i == 2) repack_k<2><<<144, 256, 0, stream>>>(sr_w[i], wt);

    if (i == 0) conv_k<8><<<BB*side*2, 256, 0, stream>>>(xb, wt, sr_b[i], tpre, side, m);
    if (i == 1) conv_k<4><<<BB*side*2, 256, 0, stream>>>(xb, wt, sr_b[i], tpre, side, m);
    if (i == 2) conv_k<2><<<BB*side*2, 256, 0, stream>>>(xb, wt, sr_b[i], tpre, side, m);

    ln_gelu_k<<<m, 256, 0, stream>>>(tpre, ln_g[i], ln_b[i], tbuf, BB*m);

    GemmP pk{}; pk.A = tbuf; pk.W = kv_w; pk.bias = kv_b; pk.outk = kbuf; pk.outv = vpre;
    pk.Mtot = BB*m; pk.m = m; pk.mtiles = (BB*m + 63)/64; pk.ntiles = 2;
    gemm_k<2,false,true><<<pk.mtiles*2, 256, 0, stream>>>(pk);

    lcconv_k<<<m, 256, 0, stream>>>(vpre, lc_w[i], lc_b[i], vtb, m, mpad, side);

    attn_k<<<BB*64, 512, 0, stream>>>(q_all, kbuf, vtb, xheads, m, mpad, i);
  }

  { // out = concat @ nn1_w^T + nn1_b -> fp32 d_out
    GemmP p{}; p.A = xheads; p.W = nn1_w; p.bias = nn1_b; p.outf = (float*)d_out;
    p.Mtot = BB*NB; p.m = BB*NB; p.mtiles = 256; p.ntiles = 3;
    gemm_k<3,false,true><<<256*3, 256, 0, stream>>>(p);
  }
}